// Round 6
// baseline (1380.885 us; speedup 1.0000x reference)
//
#include <hip/hip_runtime.h>
#include <cstdint>
#include <cstddef>

typedef __attribute__((ext_vector_type(8))) _Float16 f16x8;
typedef __attribute__((ext_vector_type(4))) float f32x4;

#define B_ROWS 16384
#define K_DIM  1024
#define H_DIM  4096
#define O_DIM  4
#define NT     32              // K_DIM / 32 K-tiles
#define XS     1088            // padded row stride (halfs) = 2176 B = 2^7 * 17
#define MARGIN 3e-3f
#define FLAG_CAP (1u<<20)

// ws layout (bytes); r2 proved ws_size >= 138412160
#define OFF_XH   ((size_t)0)                 // 16384*1088*2 = 35651584
#define OFF_WH   ((size_t)35651584)          // 4096*1088*2  =  8912896
#define OFF_BITS ((size_t)44564480)          // 16384*128*4  =  8388608
#define OFF_CNT  ((size_t)52953088)          // 128 B
#define OFF_FLG  ((size_t)52953216)          // 1M * 4 B
#define WS_NEED  ((size_t)57147520)

#define GLD16(g, l) __builtin_amdgcn_global_load_lds(                         \
    (const __attribute__((address_space(1))) void*)(g),                       \
    (__attribute__((address_space(3))) void*)(l), 16, 0, 0)

// ---------------------------------------------------------------------------
// split: f32 -> f16 (RTN) for x and W1, fused; zeroes flag counter.
// Output row stride XS halfs (padded to kill power-of-2 channel aliasing).
// ---------------------------------------------------------------------------
__global__ __launch_bounds__(256) void split_f16(
    const float* __restrict__ x, const float* __restrict__ W1,
    _Float16* __restrict__ Xh, _Float16* __restrict__ Wh,
    uint32_t* __restrict__ cnt)
{
    if (blockIdx.x == 0 && threadIdx.x == 0) *cnt = 0u;
    const int NX8 = (B_ROWS * K_DIM) / 8;
    const int NW8 = (H_DIM * K_DIM) / 8;
    const int stride = gridDim.x * blockDim.x;
    for (int i = blockIdx.x * blockDim.x + threadIdx.x; i < NX8 + NW8; i += stride) {
        const float* src; _Float16* dst; int j;
        if (i < NX8) { src = x; dst = Xh; j = i; }
        else         { src = W1; dst = Wh; j = i - NX8; }
        const float4 f0 = reinterpret_cast<const float4*>(src)[2 * j];
        const float4 f1 = reinterpret_cast<const float4*>(src)[2 * j + 1];
        f16x8 h;
        h[0] = (_Float16)f0.x; h[1] = (_Float16)f0.y;
        h[2] = (_Float16)f0.z; h[3] = (_Float16)f0.w;
        h[4] = (_Float16)f1.x; h[5] = (_Float16)f1.y;
        h[6] = (_Float16)f1.z; h[7] = (_Float16)f1.w;
        const int r = j >> 7, c = (j & 127) << 3;          // row, col (halfs)
        *reinterpret_cast<f16x8*>(dst + (size_t)r * XS + c) = h;
    }
}

// ---------------------------------------------------------------------------
// fc1: f16 MFMA GEMM, K=1024, 128x128 tile, BK=32, 4 waves.
// Identical to round-5 except operand row stride XS (anti-camping pad).
// ---------------------------------------------------------------------------
__global__ __launch_bounds__(256) void fc1_f16(
    const _Float16* __restrict__ Xh, const _Float16* __restrict__ Wh,
    const float* __restrict__ b1, uint32_t* __restrict__ bits,
    uint32_t* __restrict__ cnt, uint32_t* __restrict__ flags)
{
    __shared__ __align__(16) _Float16 As[2][128 * 32];
    __shared__ __align__(16) _Float16 Bs[2][128 * 32];

    const int tid  = threadIdx.x;
    const int lane = tid & 63;
    const int w    = tid >> 6;                 // wave 0..3
    const int m0   = blockIdx.y * 128;
    const int n0   = blockIdx.x * 128;

    // staging: lane covers row w*16 + (lane>>2) (+64), 8-half chunk lane&3 (LINEAR)
    const int   srow   = w * 16 + (lane >> 2);
    const int   schunk = (lane & 3) * 8;
    const size_t gA0 = (size_t)(m0 + srow) * XS + schunk;
    const size_t gA1 = (size_t)(m0 + srow + 64) * XS + schunk;
    const size_t gB0 = (size_t)(n0 + srow) * XS + schunk;
    const size_t gB1 = (size_t)(n0 + srow + 64) * XS + schunk;

    auto stage = [&](int buf, int t) {
        const int k0 = t * 32;
        GLD16(Xh + gA0 + k0, &As[buf][w * 512]);
        GLD16(Xh + gA1 + k0, &As[buf][2048 + w * 512]);
        GLD16(Wh + gB0 + k0, &Bs[buf][w * 512]);
        GLD16(Wh + gB1 + k0, &Bs[buf][2048 + w * 512]);
    };

    const int wr   = (w >> 1) * 64;            // wave row offset
    const int wc   = (w & 1) * 64;             // wave col offset
    const int frow = lane & 15;
    const int fk   = (lane >> 4) * 8;          // k-offset within 32 (LINEAR)

    f32x4 acc[4][4];
#pragma unroll
    for (int i = 0; i < 4; ++i)
#pragma unroll
        for (int j = 0; j < 4; ++j)
            acc[i][j] = (f32x4){0.f, 0.f, 0.f, 0.f};

    stage(0, 0);
    int buf = 0;
    for (int t = 0; t < NT; ++t) {
        __syncthreads();                       // drains stage(t)
        if (t + 1 < NT) stage(buf ^ 1, t + 1);
        f16x8 a[4], b[4];
#pragma unroll
        for (int mi = 0; mi < 4; ++mi)
            a[mi] = *reinterpret_cast<const f16x8*>(
                &As[buf][(wr + mi * 16 + frow) * 32 + fk]);
#pragma unroll
        for (int nj = 0; nj < 4; ++nj)
            b[nj] = *reinterpret_cast<const f16x8*>(
                &Bs[buf][(wc + nj * 16 + frow) * 32 + fk]);
#pragma unroll
        for (int mi = 0; mi < 4; ++mi)
#pragma unroll
            for (int nj = 0; nj < 4; ++nj)
                acc[mi][nj] = __builtin_amdgcn_mfma_f32_16x16x32_f16(
                    a[mi], b[nj], acc[mi][nj], 0, 0, 0);
        buf ^= 1;
    }

    // ---- ballot epilogue (validated): each bits-word stored once ----
    float bcol[4];
#pragma unroll
    for (int nj = 0; nj < 4; ++nj) bcol[nj] = b1[n0 + wc + nj * 16 + frow];

    const int g = lane >> 4;
#pragma unroll
    for (int mi = 0; mi < 4; ++mi) {
#pragma unroll
        for (int r = 0; r < 4; ++r) {
            unsigned long long bj[4];
#pragma unroll
            for (int nj = 0; nj < 4; ++nj) {
                const float cur = acc[mi][nj][r] + bcol[nj];
                bj[nj] = __ballot(cur > 1.0f);
                if (fabsf(cur - 1.0f) < MARGIN) {
                    uint32_t ix = atomicAdd(cnt, 1u);
                    if (ix < FLAG_CAP)
                        flags[ix] = ((uint32_t)(m0 + wr + mi * 16 + g * 4 + r) << 12)
                                  | (uint32_t)(n0 + wc + nj * 16 + frow);
                }
            }
            if (frow == 0) {
                const int row = m0 + wr + mi * 16 + g * 4 + r;
                const uint32_t w0 =
                    (uint32_t)((bj[0] >> (g * 16)) & 0xFFFFull) |
                    ((uint32_t)((bj[1] >> (g * 16)) & 0xFFFFull) << 16);
                const uint32_t w1 =
                    (uint32_t)((bj[2] >> (g * 16)) & 0xFFFFull) |
                    ((uint32_t)((bj[3] >> (g * 16)) & 0xFFFFull) << 16);
                uint2 v; v.x = w0; v.y = w1;
                *reinterpret_cast<uint2*>(
                    &bits[(size_t)row * 128 + (n0 >> 5) + (wc >> 5)]) = v;
            }
        }
    }
}

// ---------------------------------------------------------------------------
// refine: exact f64 dot for flagged (row,col); fix the spike bit.
// ---------------------------------------------------------------------------
__global__ __launch_bounds__(256) void refine(
    const float* __restrict__ x, const float* __restrict__ W1,
    const float* __restrict__ b1, const uint32_t* __restrict__ cnt,
    const uint32_t* __restrict__ flags, uint32_t* __restrict__ bits)
{
    const int lane = threadIdx.x & 63;
    const int wave = (blockIdx.x * 256 + threadIdx.x) >> 6;
    const int nw   = (gridDim.x * 256) >> 6;
    uint32_t n = *cnt; if (n > FLAG_CAP) n = FLAG_CAP;

    for (uint32_t f = wave; f < n; f += nw) {
        const uint32_t e = flags[f];
        const int row = e >> 12, col = e & 4095;
        const float4* xr = (const float4*)(x  + (size_t)row * K_DIM);
        const float4* wr = (const float4*)(W1 + (size_t)col * K_DIM);
        double s = 0.0;
#pragma unroll
        for (int i = 0; i < 4; ++i) {
            const float4 xa = xr[lane + i * 64];
            const float4 wa = wr[lane + i * 64];
            s = fma((double)xa.x, (double)wa.x, s);
            s = fma((double)xa.y, (double)wa.y, s);
            s = fma((double)xa.z, (double)wa.z, s);
            s = fma((double)xa.w, (double)wa.w, s);
        }
        for (int off = 32; off; off >>= 1) s += __shfl_down(s, off, 64);
        if (lane == 0) {
            const double cur = s + (double)b1[col];
            uint32_t* word = &bits[(size_t)row * 128 + (col >> 5)];
            const uint32_t mask = 1u << (col & 31);
            if (cur > 1.0) atomicOr(word, mask);
            else           atomicAnd(word, ~mask);
        }
    }
}

// ---------------------------------------------------------------------------
// fc2: one wave per batch row; f64 exact select-add over spike bits.
// ---------------------------------------------------------------------------
__global__ __launch_bounds__(256) void snn_fc2w(
    const uint32_t* __restrict__ bits, const float* __restrict__ W2,
    const float* __restrict__ b2, float* __restrict__ out)
{
    const int lane = threadIdx.x & 63;
    const int row  = (blockIdx.x << 2) + (threadIdx.x >> 6);
    const uint32_t w0 = bits[(size_t)row * 128 + 2 * lane];
    const uint32_t w1 = bits[(size_t)row * 128 + 2 * lane + 1];
    double acc[4];
#pragma unroll
    for (int o = 0; o < 4; ++o) {
        const float4* wrow = (const float4*)(W2 + (size_t)o * H_DIM + lane * 64);
        double a = 0.0;
#pragma unroll
        for (int q = 0; q < 16; ++q) {
            const float4 v = wrow[q];
            const uint32_t word = (q < 8) ? w0 : w1;
            const int bit = (4 * q) & 31;
            if ((word >> bit)       & 1u) a += (double)v.x;
            if ((word >> (bit + 1)) & 1u) a += (double)v.y;
            if ((word >> (bit + 2)) & 1u) a += (double)v.z;
            if ((word >> (bit + 3)) & 1u) a += (double)v.w;
        }
        acc[o] = a;
    }
#pragma unroll
    for (int off = 32; off; off >>= 1)
#pragma unroll
        for (int o = 0; o < 4; ++o) acc[o] += __shfl_down(acc[o], off, 64);
    if (lane == 0) {
#pragma unroll
        for (int o = 0; o < 4; ++o) {
            const double cur = acc[o] + (double)b2[o];
            out[row * 4 + o] = (float)cur;
            out[B_ROWS * O_DIM + row * 4 + o] = (cur > 1.0) ? 1.0f : 0.0f;
        }
    }
}

// ---------------------------------------------------------------------------
// Fallback exact-f64 fc1 (round-1 kernel) for small ws_size
// ---------------------------------------------------------------------------
#define BM 64
#define BN 64
#define BK 32
__global__ __launch_bounds__(256) void snn_fc1(
    const float* __restrict__ x, const float* __restrict__ W1,
    const float* __restrict__ b1, uint32_t* __restrict__ spk_bits)
{
    __shared__ float As[BK][68];
    __shared__ float Bs[BK][68];
    __shared__ uint32_t bitbuf[BM][BN / 32];

    const int tid = threadIdx.x;
    const int m0 = blockIdx.y * BM;
    const int n0 = blockIdx.x * BN;
    const int rm = tid & 15, cn = tid >> 4;
    const int mf = 4 * rm, nf = 4 * cn;

    double acc[4][4];
#pragma unroll
    for (int i = 0; i < 4; ++i)
#pragma unroll
        for (int j = 0; j < 4; ++j) acc[i][j] = 0.0;

    const int sm = tid >> 3, skq = tid & 7;
    for (int kt = 0; kt < K_DIM / BK; ++kt) {
        const int k0 = kt * BK;
#pragma unroll
        for (int s = 0; s < 2; ++s) {
            const int m = sm + 32 * s;
            const float4 av = *reinterpret_cast<const float4*>(
                x + (size_t)(m0 + m) * K_DIM + k0 + 4 * skq);
            As[4 * skq + 0][m] = av.x; As[4 * skq + 1][m] = av.y;
            As[4 * skq + 2][m] = av.z; As[4 * skq + 3][m] = av.w;
            const float4 bv = *reinterpret_cast<const float4*>(
                W1 + (size_t)(n0 + m) * K_DIM + k0 + 4 * skq);
            Bs[4 * skq + 0][m] = bv.x; Bs[4 * skq + 1][m] = bv.y;
            Bs[4 * skq + 2][m] = bv.z; Bs[4 * skq + 3][m] = bv.w;
        }
        __syncthreads();
#pragma unroll
        for (int k = 0; k < BK; ++k) {
            const float4 af = *reinterpret_cast<const float4*>(&As[k][mf]);
            const float4 bf = *reinterpret_cast<const float4*>(&Bs[k][nf]);
            const double a0 = af.x, a1 = af.y, a2 = af.z, a3 = af.w;
            const double b0 = bf.x, b1v = bf.y, b2v = bf.z, b3 = bf.w;
            acc[0][0] = fma(a0, b0, acc[0][0]);  acc[0][1] = fma(a0, b1v, acc[0][1]);
            acc[0][2] = fma(a0, b2v, acc[0][2]); acc[0][3] = fma(a0, b3, acc[0][3]);
            acc[1][0] = fma(a1, b0, acc[1][0]);  acc[1][1] = fma(a1, b1v, acc[1][1]);
            acc[1][2] = fma(a1, b2v, acc[1][2]); acc[1][3] = fma(a1, b3, acc[1][3]);
            acc[2][0] = fma(a2, b0, acc[2][0]);  acc[2][1] = fma(a2, b1v, acc[2][1]);
            acc[2][2] = fma(a2, b2v, acc[2][2]); acc[2][3] = fma(a2, b3, acc[2][3]);
            acc[3][0] = fma(a3, b0, acc[3][0]);  acc[3][1] = fma(a3, b1v, acc[3][1]);
            acc[3][2] = fma(a3, b2v, acc[3][2]); acc[3][3] = fma(a3, b3, acc[3][3]);
        }
        __syncthreads();
    }

    if (tid < BM * (BN / 32)) bitbuf[tid >> 1][tid & 1] = 0u;
    __syncthreads();
#pragma unroll
    for (int j = 0; j < 4; ++j) {
        const int n = nf + j;
        const double bias = (double)b1[n0 + n];
        const int wd = n >> 5, bit = n & 31;
#pragma unroll
        for (int i = 0; i < 4; ++i) {
            const double cur = acc[i][j] + bias;
            if (cur > 1.0) atomicOr(&bitbuf[mf + i][wd], 1u << bit);
        }
    }
    __syncthreads();
    if (tid < 128) {
        const int r = tid >> 1, wd = tid & 1;
        spk_bits[(size_t)(m0 + r) * (H_DIM / 32) + (n0 >> 5) + wd] = bitbuf[r][wd];
    }
}

// ---------------------------------------------------------------------------
extern "C" void kernel_launch(void* const* d_in, const int* in_sizes, int n_in,
                              void* d_out, int out_size, void* d_ws, size_t ws_size,
                              hipStream_t stream) {
    const float* x  = (const float*)d_in[0];
    const float* W1 = (const float*)d_in[1];
    const float* b1 = (const float*)d_in[2];
    const float* W2 = (const float*)d_in[3];
    const float* b2 = (const float*)d_in[4];
    float* out = (float*)d_out;
    char* ws = (char*)d_ws;

    if (ws_size >= WS_NEED) {
        _Float16* Xh   = (_Float16*)(ws + OFF_XH);
        _Float16* Wh   = (_Float16*)(ws + OFF_WH);
        uint32_t* bits = (uint32_t*)(ws + OFF_BITS);
        uint32_t* cnt  = (uint32_t*)(ws + OFF_CNT);
        uint32_t* flg  = (uint32_t*)(ws + OFF_FLG);

        split_f16<<<2048, 256, 0, stream>>>(x, W1, Xh, Wh, cnt);
        fc1_f16<<<dim3(H_DIM / 128, B_ROWS / 128), 256, 0, stream>>>(
            Xh, Wh, b1, bits, cnt, flg);
        refine<<<2048, 256, 0, stream>>>(x, W1, b1, cnt, flg, bits);
        snn_fc2w<<<B_ROWS / 4, 256, 0, stream>>>(bits, W2, b2, out);
    } else {
        uint32_t* bits = (uint32_t*)ws;
        dim3 g1(H_DIM / BN, B_ROWS / BM);
        snn_fc1<<<g1, 256, 0, stream>>>(x, W1, b1, bits);
        snn_fc2w<<<B_ROWS / 4, 256, 0, stream>>>(bits, W2, b2, out);
    }
}

// Round 7
// 461.418 us; speedup vs baseline: 2.9927x; 2.9927x over previous
//
#include <hip/hip_runtime.h>
#include <cstdint>
#include <cstddef>

typedef __attribute__((ext_vector_type(8))) _Float16 f16x8;
typedef __attribute__((ext_vector_type(4))) float f32x4;

#define B_ROWS 16384
#define K_DIM  1024
#define H_DIM  4096
#define O_DIM  4
#define NT     32              // K_DIM / 32 K-tiles
#define MARGIN 3e-3f
#define FLAG_CAP (1u<<20)
#define STASH_CAP 1024

// ws layout (bytes)
#define OFF_XH   ((size_t)0)                 // 16384*1024*2 = 33554432
#define OFF_WH   ((size_t)33554432)          // 4096*1024*2  =  8388608
#define OFF_BITS ((size_t)41943040)          // 16384*128*4  =  8388608
#define OFF_CNT  ((size_t)50331648)          // 128 B
#define OFF_FLG  ((size_t)50331776)          // 1M * 4 B
#define WS_NEED  ((size_t)54526080)

#define GLD16(g, l) __builtin_amdgcn_global_load_lds(                         \
    (const __attribute__((address_space(1))) void*)(g),                       \
    (__attribute__((address_space(3))) void*)(l), 16, 0, 0)

// ---------------------------------------------------------------------------
// split: f32 -> f16 (RTN) for x and W1, fused; zeroes flag counter.
// ---------------------------------------------------------------------------
__global__ __launch_bounds__(256) void split_f16(
    const float* __restrict__ x, const float* __restrict__ W1,
    _Float16* __restrict__ Xh, _Float16* __restrict__ Wh,
    uint32_t* __restrict__ cnt)
{
    if (blockIdx.x == 0 && threadIdx.x == 0) *cnt = 0u;
    const int NX8 = (B_ROWS * K_DIM) / 8;
    const int NW8 = (H_DIM * K_DIM) / 8;
    const int stride = gridDim.x * blockDim.x;
    for (int i = blockIdx.x * blockDim.x + threadIdx.x; i < NX8 + NW8; i += stride) {
        const float* src; _Float16* dst; int j;
        if (i < NX8) { src = x; dst = Xh; j = i; }
        else         { src = W1; dst = Wh; j = i - NX8; }
        const float4 f0 = reinterpret_cast<const float4*>(src)[2 * j];
        const float4 f1 = reinterpret_cast<const float4*>(src)[2 * j + 1];
        f16x8 h;
        h[0] = (_Float16)f0.x; h[1] = (_Float16)f0.y;
        h[2] = (_Float16)f0.z; h[3] = (_Float16)f0.w;
        h[4] = (_Float16)f1.x; h[5] = (_Float16)f1.y;
        h[6] = (_Float16)f1.z; h[7] = (_Float16)f1.w;
        reinterpret_cast<f16x8*>(dst)[j] = h;
    }
}

// ---------------------------------------------------------------------------
// fc1: f16 MFMA GEMM, K=1024, 128x128 tile, BK=32, 4 waves.
// Loop identical to round 5. Epilogue: ballot bits + PER-BLOCK LDS flag stash
// (one global atomicAdd per block instead of ~100K same-address atomics).
// ---------------------------------------------------------------------------
__global__ __launch_bounds__(256) void fc1_f16(
    const _Float16* __restrict__ Xh, const _Float16* __restrict__ Wh,
    const float* __restrict__ b1, uint32_t* __restrict__ bits,
    uint32_t* __restrict__ cnt, uint32_t* __restrict__ flags)
{
    __shared__ __align__(16) _Float16 As[2][128 * 32];
    __shared__ __align__(16) _Float16 Bs[2][128 * 32];
    __shared__ uint32_t scnt, sbase;

    const int tid  = threadIdx.x;
    const int lane = tid & 63;
    const int w    = tid >> 6;                 // wave 0..3
    const int m0   = blockIdx.y * 128;
    const int n0   = blockIdx.x * 128;

    // staging: lane covers row w*16 + (lane>>2) (+64), 8-half chunk lane&3
    const int   srow   = w * 16 + (lane >> 2);
    const int   schunk = (lane & 3) * 8;
    const size_t gA0 = (size_t)(m0 + srow) * K_DIM + schunk;
    const size_t gA1 = (size_t)(m0 + srow + 64) * K_DIM + schunk;
    const size_t gB0 = (size_t)(n0 + srow) * K_DIM + schunk;
    const size_t gB1 = (size_t)(n0 + srow + 64) * K_DIM + schunk;

    auto stage = [&](int buf, int t) {
        const int k0 = t * 32;
        GLD16(Xh + gA0 + k0, &As[buf][w * 512]);
        GLD16(Xh + gA1 + k0, &As[buf][2048 + w * 512]);
        GLD16(Wh + gB0 + k0, &Bs[buf][w * 512]);
        GLD16(Wh + gB1 + k0, &Bs[buf][2048 + w * 512]);
    };

    const int wr   = (w >> 1) * 64;            // wave row offset
    const int wc   = (w & 1) * 64;             // wave col offset
    const int frow = lane & 15;
    const int fk   = (lane >> 4) * 8;          // k-offset within 32

    f32x4 acc[4][4];
#pragma unroll
    for (int i = 0; i < 4; ++i)
#pragma unroll
        for (int j = 0; j < 4; ++j)
            acc[i][j] = (f32x4){0.f, 0.f, 0.f, 0.f};

    stage(0, 0);
    int buf = 0;
    for (int t = 0; t < NT; ++t) {
        __syncthreads();                       // drains stage(t)
        if (t + 1 < NT) stage(buf ^ 1, t + 1);
        f16x8 a[4], b[4];
#pragma unroll
        for (int mi = 0; mi < 4; ++mi)
            a[mi] = *reinterpret_cast<const f16x8*>(
                &As[buf][(wr + mi * 16 + frow) * 32 + fk]);
#pragma unroll
        for (int nj = 0; nj < 4; ++nj)
            b[nj] = *reinterpret_cast<const f16x8*>(
                &Bs[buf][(wc + nj * 16 + frow) * 32 + fk]);
#pragma unroll
        for (int mi = 0; mi < 4; ++mi)
#pragma unroll
            for (int nj = 0; nj < 4; ++nj)
                acc[mi][nj] = __builtin_amdgcn_mfma_f32_16x16x32_f16(
                    a[mi], b[nj], acc[mi][nj], 0, 0, 0);
        buf ^= 1;
    }

    // ---- epilogue: ballot bits + LDS flag stash ----
    __syncthreads();                           // staged data now dead; reuse As
    uint32_t* stash = (uint32_t*)&As[0][0];    // 1024 * 4 B
    if (tid == 0) scnt = 0u;
    __syncthreads();

    float bcol[4];
#pragma unroll
    for (int nj = 0; nj < 4; ++nj) bcol[nj] = b1[n0 + wc + nj * 16 + frow];

    const int g = lane >> 4;
#pragma unroll
    for (int mi = 0; mi < 4; ++mi) {
#pragma unroll
        for (int r = 0; r < 4; ++r) {
            unsigned long long bj[4];
#pragma unroll
            for (int nj = 0; nj < 4; ++nj) {
                const float cur = acc[mi][nj][r] + bcol[nj];
                bj[nj] = __ballot(cur > 1.0f);
                if (fabsf(cur - 1.0f) < MARGIN) {
                    const uint32_t enc =
                        ((uint32_t)(m0 + wr + mi * 16 + g * 4 + r) << 12)
                      | (uint32_t)(n0 + wc + nj * 16 + frow);
                    uint32_t ix = atomicAdd(&scnt, 1u);
                    if (ix < STASH_CAP) {
                        stash[ix] = enc;
                    } else {                   // overflow: direct (rare/never)
                        uint32_t gx = atomicAdd(cnt, 1u);
                        if (gx < FLAG_CAP) flags[gx] = enc;
                    }
                }
            }
            if (frow == 0) {
                const int row = m0 + wr + mi * 16 + g * 4 + r;
                const uint32_t w0 =
                    (uint32_t)((bj[0] >> (g * 16)) & 0xFFFFull) |
                    ((uint32_t)((bj[1] >> (g * 16)) & 0xFFFFull) << 16);
                const uint32_t w1 =
                    (uint32_t)((bj[2] >> (g * 16)) & 0xFFFFull) |
                    ((uint32_t)((bj[3] >> (g * 16)) & 0xFFFFull) << 16);
                uint2 v; v.x = w0; v.y = w1;
                *reinterpret_cast<uint2*>(
                    &bits[(size_t)row * 128 + (n0 >> 5) + (wc >> 5)]) = v;
            }
        }
    }
    __syncthreads();

    const uint32_t c = (scnt < STASH_CAP) ? scnt : STASH_CAP;
    if (tid == 0) sbase = atomicAdd(cnt, c);   // ONE global atomic per block
    __syncthreads();
    for (uint32_t i = tid; i < c; i += 256) {
        const uint32_t gx = sbase + i;
        if (gx < FLAG_CAP) flags[gx] = stash[i];
    }
}

// ---------------------------------------------------------------------------
// refine: exact f64 dot for flagged (row,col); fix the spike bit.
// ---------------------------------------------------------------------------
__global__ __launch_bounds__(256) void refine(
    const float* __restrict__ x, const float* __restrict__ W1,
    const float* __restrict__ b1, const uint32_t* __restrict__ cnt,
    const uint32_t* __restrict__ flags, uint32_t* __restrict__ bits)
{
    const int lane = threadIdx.x & 63;
    const int wave = (blockIdx.x * 256 + threadIdx.x) >> 6;
    const int nw   = (gridDim.x * 256) >> 6;
    uint32_t n = *cnt; if (n > FLAG_CAP) n = FLAG_CAP;

    for (uint32_t f = wave; f < n; f += nw) {
        const uint32_t e = flags[f];
        const int row = e >> 12, col = e & 4095;
        const float4* xr = (const float4*)(x  + (size_t)row * K_DIM);
        const float4* wr = (const float4*)(W1 + (size_t)col * K_DIM);
        double s = 0.0;
#pragma unroll
        for (int i = 0; i < 4; ++i) {
            const float4 xa = xr[lane + i * 64];
            const float4 wa = wr[lane + i * 64];
            s = fma((double)xa.x, (double)wa.x, s);
            s = fma((double)xa.y, (double)wa.y, s);
            s = fma((double)xa.z, (double)wa.z, s);
            s = fma((double)xa.w, (double)wa.w, s);
        }
        for (int off = 32; off; off >>= 1) s += __shfl_down(s, off, 64);
        if (lane == 0) {
            const double cur = s + (double)b1[col];
            uint32_t* word = &bits[(size_t)row * 128 + (col >> 5)];
            const uint32_t mask = 1u << (col & 31);
            if (cur > 1.0) atomicOr(word, mask);
            else           atomicAnd(word, ~mask);
        }
    }
}

// ---------------------------------------------------------------------------
// fc2: one wave per batch row; f64 exact select-add over spike bits.
// ---------------------------------------------------------------------------
__global__ __launch_bounds__(256) void snn_fc2w(
    const uint32_t* __restrict__ bits, const float* __restrict__ W2,
    const float* __restrict__ b2, float* __restrict__ out)
{
    const int lane = threadIdx.x & 63;
    const int row  = (blockIdx.x << 2) + (threadIdx.x >> 6);
    const uint32_t w0 = bits[(size_t)row * 128 + 2 * lane];
    const uint32_t w1 = bits[(size_t)row * 128 + 2 * lane + 1];
    double acc[4];
#pragma unroll
    for (int o = 0; o < 4; ++o) {
        const float4* wrow = (const float4*)(W2 + (size_t)o * H_DIM + lane * 64);
        double a = 0.0;
#pragma unroll
        for (int q = 0; q < 16; ++q) {
            const float4 v = wrow[q];
            const uint32_t word = (q < 8) ? w0 : w1;
            const int bit = (4 * q) & 31;
            if ((word >> bit)       & 1u) a += (double)v.x;
            if ((word >> (bit + 1)) & 1u) a += (double)v.y;
            if ((word >> (bit + 2)) & 1u) a += (double)v.z;
            if ((word >> (bit + 3)) & 1u) a += (double)v.w;
        }
        acc[o] = a;
    }
#pragma unroll
    for (int off = 32; off; off >>= 1)
#pragma unroll
        for (int o = 0; o < 4; ++o) acc[o] += __shfl_down(acc[o], off, 64);
    if (lane == 0) {
#pragma unroll
        for (int o = 0; o < 4; ++o) {
            const double cur = acc[o] + (double)b2[o];
            out[row * 4 + o] = (float)cur;
            out[B_ROWS * O_DIM + row * 4 + o] = (cur > 1.0) ? 1.0f : 0.0f;
        }
    }
}

// ---------------------------------------------------------------------------
// Fallback exact-f64 fc1 (round-1 kernel) for small ws_size
// ---------------------------------------------------------------------------
#define BM 64
#define BN 64
#define BK 32
__global__ __launch_bounds__(256) void snn_fc1(
    const float* __restrict__ x, const float* __restrict__ W1,
    const float* __restrict__ b1, uint32_t* __restrict__ spk_bits)
{
    __shared__ float As[BK][68];
    __shared__ float Bs[BK][68];
    __shared__ uint32_t bitbuf[BM][BN / 32];

    const int tid = threadIdx.x;
    const int m0 = blockIdx.y * BM;
    const int n0 = blockIdx.x * BN;
    const int rm = tid & 15, cn = tid >> 4;
    const int mf = 4 * rm, nf = 4 * cn;

    double acc[4][4];
#pragma unroll
    for (int i = 0; i < 4; ++i)
#pragma unroll
        for (int j = 0; j < 4; ++j) acc[i][j] = 0.0;

    const int sm = tid >> 3, skq = tid & 7;
    for (int kt = 0; kt < K_DIM / BK; ++kt) {
        const int k0 = kt * BK;
#pragma unroll
        for (int s = 0; s < 2; ++s) {
            const int m = sm + 32 * s;
            const float4 av = *reinterpret_cast<const float4*>(
                x + (size_t)(m0 + m) * K_DIM + k0 + 4 * skq);
            As[4 * skq + 0][m] = av.x; As[4 * skq + 1][m] = av.y;
            As[4 * skq + 2][m] = av.z; As[4 * skq + 3][m] = av.w;
            const float4 bv = *reinterpret_cast<const float4*>(
                W1 + (size_t)(n0 + m) * K_DIM + k0 + 4 * skq);
            Bs[4 * skq + 0][m] = bv.x; Bs[4 * skq + 1][m] = bv.y;
            Bs[4 * skq + 2][m] = bv.z; Bs[4 * skq + 3][m] = bv.w;
        }
        __syncthreads();
#pragma unroll
        for (int k = 0; k < BK; ++k) {
            const float4 af = *reinterpret_cast<const float4*>(&As[k][mf]);
            const float4 bf = *reinterpret_cast<const float4*>(&Bs[k][nf]);
            const double a0 = af.x, a1 = af.y, a2 = af.z, a3 = af.w;
            const double b0 = bf.x, b1v = bf.y, b2v = bf.z, b3 = bf.w;
            acc[0][0] = fma(a0, b0, acc[0][0]);  acc[0][1] = fma(a0, b1v, acc[0][1]);
            acc[0][2] = fma(a0, b2v, acc[0][2]); acc[0][3] = fma(a0, b3, acc[0][3]);
            acc[1][0] = fma(a1, b0, acc[1][0]);  acc[1][1] = fma(a1, b1v, acc[1][1]);
            acc[1][2] = fma(a1, b2v, acc[1][2]); acc[1][3] = fma(a1, b3, acc[1][3]);
            acc[2][0] = fma(a2, b0, acc[2][0]);  acc[2][1] = fma(a2, b1v, acc[2][1]);
            acc[2][2] = fma(a2, b2v, acc[2][2]); acc[2][3] = fma(a2, b3, acc[2][3]);
            acc[3][0] = fma(a3, b0, acc[3][0]);  acc[3][1] = fma(a3, b1v, acc[3][1]);
            acc[3][2] = fma(a3, b2v, acc[3][2]); acc[3][3] = fma(a3, b3, acc[3][3]);
        }
        __syncthreads();
    }

    if (tid < BM * (BN / 32)) bitbuf[tid >> 1][tid & 1] = 0u;
    __syncthreads();
#pragma unroll
    for (int j = 0; j < 4; ++j) {
        const int n = nf + j;
        const double bias = (double)b1[n0 + n];
        const int wd = n >> 5, bit = n & 31;
#pragma unroll
        for (int i = 0; i < 4; ++i) {
            const double cur = acc[i][j] + bias;
            if (cur > 1.0) atomicOr(&bitbuf[mf + i][wd], 1u << bit);
        }
    }
    __syncthreads();
    if (tid < 128) {
        const int r = tid >> 1, wd = tid & 1;
        spk_bits[(size_t)(m0 + r) * (H_DIM / 32) + (n0 >> 5) + wd] = bitbuf[r][wd];
    }
}

// ---------------------------------------------------------------------------
extern "C" void kernel_launch(void* const* d_in, const int* in_sizes, int n_in,
                              void* d_out, int out_size, void* d_ws, size_t ws_size,
                              hipStream_t stream) {
    const float* x  = (const float*)d_in[0];
    const float* W1 = (const float*)d_in[1];
    const float* b1 = (const float*)d_in[2];
    const float* W2 = (const float*)d_in[3];
    const float* b2 = (const float*)d_in[4];
    float* out = (float*)d_out;
    char* ws = (char*)d_ws;

    if (ws_size >= WS_NEED) {
        _Float16* Xh   = (_Float16*)(ws + OFF_XH);
        _Float16* Wh   = (_Float16*)(ws + OFF_WH);
        uint32_t* bits = (uint32_t*)(ws + OFF_BITS);
        uint32_t* cnt  = (uint32_t*)(ws + OFF_CNT);
        uint32_t* flg  = (uint32_t*)(ws + OFF_FLG);

        split_f16<<<2048, 256, 0, stream>>>(x, W1, Xh, Wh, cnt);
        fc1_f16<<<dim3(H_DIM / 128, B_ROWS / 128), 256, 0, stream>>>(
            Xh, Wh, b1, bits, cnt, flg);
        refine<<<2048, 256, 0, stream>>>(x, W1, b1, cnt, flg, bits);
        snn_fc2w<<<B_ROWS / 4, 256, 0, stream>>>(bits, W2, b2, out);
    } else {
        uint32_t* bits = (uint32_t*)ws;
        dim3 g1(H_DIM / BN, B_ROWS / BM);
        snn_fc1<<<g1, 256, 0, stream>>>(x, W1, b1, bits);
        snn_fc2w<<<B_ROWS / 4, 256, 0, stream>>>(bits, W2, b2, out);
    }
}

// Round 8
// 458.690 us; speedup vs baseline: 3.0105x; 1.0059x over previous
//
#include <hip/hip_runtime.h>
#include <cstdint>
#include <cstddef>

typedef __attribute__((ext_vector_type(8))) _Float16 f16x8;
typedef __attribute__((ext_vector_type(4))) float f32x4;

#define B_ROWS 16384
#define K_DIM  1024
#define H_DIM  4096
#define O_DIM  4
#define NT     32              // K_DIM / 32 K-tiles
#define MARGIN 3e-3f
#define FLAG_CAP (1u<<20)
#define STASH_CAP 1024

// ws layout (bytes)
#define OFF_XH   ((size_t)0)                 // 16384*1024*2 = 33554432
#define OFF_WH   ((size_t)33554432)          // 4096*1024*2  =  8388608
#define OFF_BITS ((size_t)41943040)          // 16384*128*4  =  8388608
#define OFF_CNT  ((size_t)50331648)          // 128 B
#define OFF_FLG  ((size_t)50331776)          // 1M * 4 B
#define WS_NEED  ((size_t)54526080)

#define GLD16(g, l) __builtin_amdgcn_global_load_lds(                         \
    (const __attribute__((address_space(1))) void*)(g),                       \
    (__attribute__((address_space(3))) void*)(l), 16, 0, 0)

// ---------------------------------------------------------------------------
// split: f32 -> f16 (RTN) for x and W1, fused; zeroes flag counter.
// ---------------------------------------------------------------------------
__global__ __launch_bounds__(256) void split_f16(
    const float* __restrict__ x, const float* __restrict__ W1,
    _Float16* __restrict__ Xh, _Float16* __restrict__ Wh,
    uint32_t* __restrict__ cnt)
{
    if (blockIdx.x == 0 && threadIdx.x == 0) *cnt = 0u;
    const int NX8 = (B_ROWS * K_DIM) / 8;
    const int NW8 = (H_DIM * K_DIM) / 8;
    const int stride = gridDim.x * blockDim.x;
    for (int i = blockIdx.x * blockDim.x + threadIdx.x; i < NX8 + NW8; i += stride) {
        const float* src; _Float16* dst; int j;
        if (i < NX8) { src = x; dst = Xh; j = i; }
        else         { src = W1; dst = Wh; j = i - NX8; }
        const float4 f0 = reinterpret_cast<const float4*>(src)[2 * j];
        const float4 f1 = reinterpret_cast<const float4*>(src)[2 * j + 1];
        f16x8 h;
        h[0] = (_Float16)f0.x; h[1] = (_Float16)f0.y;
        h[2] = (_Float16)f0.z; h[3] = (_Float16)f0.w;
        h[4] = (_Float16)f1.x; h[5] = (_Float16)f1.y;
        h[6] = (_Float16)f1.z; h[7] = (_Float16)f1.w;
        reinterpret_cast<f16x8*>(dst)[j] = h;
    }
}

// ---------------------------------------------------------------------------
// fc1: f16 MFMA GEMM, K=1024, 128x128 tile, BK=32, 4 waves.
// r7 loop + chunk-XOR LDS swizzle (source-side inverse + read-side, rule 21;
// zeroed SQ_LDS_BANK_CONFLICT in r4). Epilogue: ballot bits + LDS flag stash.
// ---------------------------------------------------------------------------
__global__ __launch_bounds__(256) void fc1_f16(
    const _Float16* __restrict__ Xh, const _Float16* __restrict__ Wh,
    const float* __restrict__ b1, uint32_t* __restrict__ bits,
    uint32_t* __restrict__ cnt, uint32_t* __restrict__ flags)
{
    __shared__ __align__(16) _Float16 As[2][128 * 32];
    __shared__ __align__(16) _Float16 Bs[2][128 * 32];
    __shared__ uint32_t scnt, sbase;

    const int tid  = threadIdx.x;
    const int lane = tid & 63;
    const int w    = tid >> 6;                 // wave 0..3
    const int m0   = blockIdx.y * 128;
    const int n0   = blockIdx.x * 128;

    // staging: lane covers row w*16 + (lane>>2) (+64); 16B chunk = (lane&3)
    // XOR'd with (row>>1)&3 on the GLOBAL side (LDS dest stays linear).
    // Within a row the 4 lanes still cover the same 64B line -> coalescing kept.
    const int   srow   = w * 16 + (lane >> 2);
    const int   schunk = (((lane & 3) ^ ((srow >> 1) & 3)) << 3);  // halfs
    const size_t gA0 = (size_t)(m0 + srow) * K_DIM + schunk;
    const size_t gA1 = (size_t)(m0 + srow + 64) * K_DIM + schunk;
    const size_t gB0 = (size_t)(n0 + srow) * K_DIM + schunk;
    const size_t gB1 = (size_t)(n0 + srow + 64) * K_DIM + schunk;

    auto stage = [&](int buf, int t) {
        const int k0 = t * 32;
        GLD16(Xh + gA0 + k0, &As[buf][w * 512]);
        GLD16(Xh + gA1 + k0, &As[buf][2048 + w * 512]);
        GLD16(Wh + gB0 + k0, &Bs[buf][w * 512]);
        GLD16(Wh + gB1 + k0, &Bs[buf][2048 + w * 512]);
    };

    const int wr   = (w >> 1) * 64;            // wave row offset
    const int wc   = (w & 1) * 64;             // wave col offset
    const int frow = lane & 15;
    // read-side swizzled chunk: fkc ^ ((row>>1)&3); (row>>1)&3 == (frow>>1)&3
    // for all mi/nj since wr, wc, mi*16 are multiples of 8.
    const int rsw  = (((lane >> 4) ^ ((frow >> 1) & 3)) << 3);     // halfs

    f32x4 acc[4][4];
#pragma unroll
    for (int i = 0; i < 4; ++i)
#pragma unroll
        for (int j = 0; j < 4; ++j)
            acc[i][j] = (f32x4){0.f, 0.f, 0.f, 0.f};

    stage(0, 0);
    int buf = 0;
    for (int t = 0; t < NT; ++t) {
        __syncthreads();                       // drains stage(t)
        if (t + 1 < NT) stage(buf ^ 1, t + 1);
        f16x8 a[4], b[4];
#pragma unroll
        for (int mi = 0; mi < 4; ++mi)
            a[mi] = *reinterpret_cast<const f16x8*>(
                &As[buf][(wr + mi * 16 + frow) * 32 + rsw]);
#pragma unroll
        for (int nj = 0; nj < 4; ++nj)
            b[nj] = *reinterpret_cast<const f16x8*>(
                &Bs[buf][(wc + nj * 16 + frow) * 32 + rsw]);
#pragma unroll
        for (int mi = 0; mi < 4; ++mi)
#pragma unroll
            for (int nj = 0; nj < 4; ++nj)
                acc[mi][nj] = __builtin_amdgcn_mfma_f32_16x16x32_f16(
                    a[mi], b[nj], acc[mi][nj], 0, 0, 0);
        buf ^= 1;
    }

    // ---- epilogue: ballot bits + LDS flag stash ----
    __syncthreads();                           // staged data now dead; reuse As
    uint32_t* stash = (uint32_t*)&As[0][0];    // 1024 * 4 B
    if (tid == 0) scnt = 0u;
    __syncthreads();

    float bcol[4];
#pragma unroll
    for (int nj = 0; nj < 4; ++nj) bcol[nj] = b1[n0 + wc + nj * 16 + frow];

    const int g = lane >> 4;
#pragma unroll
    for (int mi = 0; mi < 4; ++mi) {
#pragma unroll
        for (int r = 0; r < 4; ++r) {
            unsigned long long bj[4];
#pragma unroll
            for (int nj = 0; nj < 4; ++nj) {
                const float cur = acc[mi][nj][r] + bcol[nj];
                bj[nj] = __ballot(cur > 1.0f);
                if (fabsf(cur - 1.0f) < MARGIN) {
                    const uint32_t enc =
                        ((uint32_t)(m0 + wr + mi * 16 + g * 4 + r) << 12)
                      | (uint32_t)(n0 + wc + nj * 16 + frow);
                    uint32_t ix = atomicAdd(&scnt, 1u);
                    if (ix < STASH_CAP) {
                        stash[ix] = enc;
                    } else {                   // overflow: direct (rare/never)
                        uint32_t gx = atomicAdd(cnt, 1u);
                        if (gx < FLAG_CAP) flags[gx] = enc;
                    }
                }
            }
            if (frow == 0) {
                const int row = m0 + wr + mi * 16 + g * 4 + r;
                const uint32_t w0 =
                    (uint32_t)((bj[0] >> (g * 16)) & 0xFFFFull) |
                    ((uint32_t)((bj[1] >> (g * 16)) & 0xFFFFull) << 16);
                const uint32_t w1 =
                    (uint32_t)((bj[2] >> (g * 16)) & 0xFFFFull) |
                    ((uint32_t)((bj[3] >> (g * 16)) & 0xFFFFull) << 16);
                uint2 v; v.x = w0; v.y = w1;
                *reinterpret_cast<uint2*>(
                    &bits[(size_t)row * 128 + (n0 >> 5) + (wc >> 5)]) = v;
            }
        }
    }
    __syncthreads();

    const uint32_t c = (scnt < STASH_CAP) ? scnt : STASH_CAP;
    if (tid == 0) sbase = atomicAdd(cnt, c);   // ONE global atomic per block
    __syncthreads();
    for (uint32_t i = tid; i < c; i += 256) {
        const uint32_t gx = sbase + i;
        if (gx < FLAG_CAP) flags[gx] = stash[i];
    }
}

// ---------------------------------------------------------------------------
// refine: exact f64 dot for flagged (row,col); fix the spike bit.
// ---------------------------------------------------------------------------
__global__ __launch_bounds__(256) void refine(
    const float* __restrict__ x, const float* __restrict__ W1,
    const float* __restrict__ b1, const uint32_t* __restrict__ cnt,
    const uint32_t* __restrict__ flags, uint32_t* __restrict__ bits)
{
    const int lane = threadIdx.x & 63;
    const int wave = (blockIdx.x * 256 + threadIdx.x) >> 6;
    const int nw   = (gridDim.x * 256) >> 6;
    uint32_t n = *cnt; if (n > FLAG_CAP) n = FLAG_CAP;

    for (uint32_t f = wave; f < n; f += nw) {
        const uint32_t e = flags[f];
        const int row = e >> 12, col = e & 4095;
        const float4* xr = (const float4*)(x  + (size_t)row * K_DIM);
        const float4* wr = (const float4*)(W1 + (size_t)col * K_DIM);
        double s = 0.0;
#pragma unroll
        for (int i = 0; i < 4; ++i) {
            const float4 xa = xr[lane + i * 64];
            const float4 wa = wr[lane + i * 64];
            s = fma((double)xa.x, (double)wa.x, s);
            s = fma((double)xa.y, (double)wa.y, s);
            s = fma((double)xa.z, (double)wa.z, s);
            s = fma((double)xa.w, (double)wa.w, s);
        }
        for (int off = 32; off; off >>= 1) s += __shfl_down(s, off, 64);
        if (lane == 0) {
            const double cur = s + (double)b1[col];
            uint32_t* word = &bits[(size_t)row * 128 + (col >> 5)];
            const uint32_t mask = 1u << (col & 31);
            if (cur > 1.0) atomicOr(word, mask);
            else           atomicAnd(word, ~mask);
        }
    }
}

// ---------------------------------------------------------------------------
// fc2: one wave per batch row; f64 exact select-add over spike bits.
// ---------------------------------------------------------------------------
__global__ __launch_bounds__(256) void snn_fc2w(
    const uint32_t* __restrict__ bits, const float* __restrict__ W2,
    const float* __restrict__ b2, float* __restrict__ out)
{
    const int lane = threadIdx.x & 63;
    const int row  = (blockIdx.x << 2) + (threadIdx.x >> 6);
    const uint32_t w0 = bits[(size_t)row * 128 + 2 * lane];
    const uint32_t w1 = bits[(size_t)row * 128 + 2 * lane + 1];
    double acc[4];
#pragma unroll
    for (int o = 0; o < 4; ++o) {
        const float4* wrow = (const float4*)(W2 + (size_t)o * H_DIM + lane * 64);
        double a = 0.0;
#pragma unroll
        for (int q = 0; q < 16; ++q) {
            const float4 v = wrow[q];
            const uint32_t word = (q < 8) ? w0 : w1;
            const int bit = (4 * q) & 31;
            if ((word >> bit)       & 1u) a += (double)v.x;
            if ((word >> (bit + 1)) & 1u) a += (double)v.y;
            if ((word >> (bit + 2)) & 1u) a += (double)v.z;
            if ((word >> (bit + 3)) & 1u) a += (double)v.w;
        }
        acc[o] = a;
    }
#pragma unroll
    for (int off = 32; off; off >>= 1)
#pragma unroll
        for (int o = 0; o < 4; ++o) acc[o] += __shfl_down(acc[o], off, 64);
    if (lane == 0) {
#pragma unroll
        for (int o = 0; o < 4; ++o) {
            const double cur = acc[o] + (double)b2[o];
            out[row * 4 + o] = (float)cur;
            out[B_ROWS * O_DIM + row * 4 + o] = (cur > 1.0) ? 1.0f : 0.0f;
        }
    }
}

// ---------------------------------------------------------------------------
// Fallback exact-f64 fc1 (round-1 kernel) for small ws_size
// ---------------------------------------------------------------------------
#define BM 64
#define BN 64
#define BK 32
__global__ __launch_bounds__(256) void snn_fc1(
    const float* __restrict__ x, const float* __restrict__ W1,
    const float* __restrict__ b1, uint32_t* __restrict__ spk_bits)
{
    __shared__ float As[BK][68];
    __shared__ float Bs[BK][68];
    __shared__ uint32_t bitbuf[BM][BN / 32];

    const int tid = threadIdx.x;
    const int m0 = blockIdx.y * BM;
    const int n0 = blockIdx.x * BN;
    const int rm = tid & 15, cn = tid >> 4;
    const int mf = 4 * rm, nf = 4 * cn;

    double acc[4][4];
#pragma unroll
    for (int i = 0; i < 4; ++i)
#pragma unroll
        for (int j = 0; j < 4; ++j) acc[i][j] = 0.0;

    const int sm = tid >> 3, skq = tid & 7;
    for (int kt = 0; kt < K_DIM / BK; ++kt) {
        const int k0 = kt * BK;
#pragma unroll
        for (int s = 0; s < 2; ++s) {
            const int m = sm + 32 * s;
            const float4 av = *reinterpret_cast<const float4*>(
                x + (size_t)(m0 + m) * K_DIM + k0 + 4 * skq);
            As[4 * skq + 0][m] = av.x; As[4 * skq + 1][m] = av.y;
            As[4 * skq + 2][m] = av.z; As[4 * skq + 3][m] = av.w;
            const float4 bv = *reinterpret_cast<const float4*>(
                W1 + (size_t)(n0 + m) * K_DIM + k0 + 4 * skq);
            Bs[4 * skq + 0][m] = bv.x; Bs[4 * skq + 1][m] = bv.y;
            Bs[4 * skq + 2][m] = bv.z; Bs[4 * skq + 3][m] = bv.w;
        }
        __syncthreads();
#pragma unroll
        for (int k = 0; k < BK; ++k) {
            const float4 af = *reinterpret_cast<const float4*>(&As[k][mf]);
            const float4 bf = *reinterpret_cast<const float4*>(&Bs[k][nf]);
            const double a0 = af.x, a1 = af.y, a2 = af.z, a3 = af.w;
            const double b0 = bf.x, b1v = bf.y, b2v = bf.z, b3 = bf.w;
            acc[0][0] = fma(a0, b0, acc[0][0]);  acc[0][1] = fma(a0, b1v, acc[0][1]);
            acc[0][2] = fma(a0, b2v, acc[0][2]); acc[0][3] = fma(a0, b3, acc[0][3]);
            acc[1][0] = fma(a1, b0, acc[1][0]);  acc[1][1] = fma(a1, b1v, acc[1][1]);
            acc[1][2] = fma(a1, b2v, acc[1][2]); acc[1][3] = fma(a1, b3, acc[1][3]);
            acc[2][0] = fma(a2, b0, acc[2][0]);  acc[2][1] = fma(a2, b1v, acc[2][1]);
            acc[2][2] = fma(a2, b2v, acc[2][2]); acc[2][3] = fma(a2, b3, acc[2][3]);
            acc[3][0] = fma(a3, b0, acc[3][0]);  acc[3][1] = fma(a3, b1v, acc[3][1]);
            acc[3][2] = fma(a3, b2v, acc[3][2]); acc[3][3] = fma(a3, b3, acc[3][3]);
        }
        __syncthreads();
    }

    if (tid < BM * (BN / 32)) bitbuf[tid >> 1][tid & 1] = 0u;
    __syncthreads();
#pragma unroll
    for (int j = 0; j < 4; ++j) {
        const int n = nf + j;
        const double bias = (double)b1[n0 + n];
        const int wd = n >> 5, bit = n & 31;
#pragma unroll
        for (int i = 0; i < 4; ++i) {
            const double cur = acc[i][j] + bias;
            if (cur > 1.0) atomicOr(&bitbuf[mf + i][wd], 1u << bit);
        }
    }
    __syncthreads();
    if (tid < 128) {
        const int r = tid >> 1, wd = tid & 1;
        spk_bits[(size_t)(m0 + r) * (H_DIM / 32) + (n0 >> 5) + wd] = bitbuf[r][wd];
    }
}

// ---------------------------------------------------------------------------
extern "C" void kernel_launch(void* const* d_in, const int* in_sizes, int n_in,
                              void* d_out, int out_size, void* d_ws, size_t ws_size,
                              hipStream_t stream) {
    const float* x  = (const float*)d_in[0];
    const float* W1 = (const float*)d_in[1];
    const float* b1 = (const float*)d_in[2];
    const float* W2 = (const float*)d_in[3];
    const float* b2 = (const float*)d_in[4];
    float* out = (float*)d_out;
    char* ws = (char*)d_ws;

    if (ws_size >= WS_NEED) {
        _Float16* Xh   = (_Float16*)(ws + OFF_XH);
        _Float16* Wh   = (_Float16*)(ws + OFF_WH);
        uint32_t* bits = (uint32_t*)(ws + OFF_BITS);
        uint32_t* cnt  = (uint32_t*)(ws + OFF_CNT);
        uint32_t* flg  = (uint32_t*)(ws + OFF_FLG);

        split_f16<<<2048, 256, 0, stream>>>(x, W1, Xh, Wh, cnt);
        fc1_f16<<<dim3(H_DIM / 128, B_ROWS / 128), 256, 0, stream>>>(
            Xh, Wh, b1, bits, cnt, flg);
        refine<<<4096, 256, 0, stream>>>(x, W1, b1, cnt, flg, bits);
        snn_fc2w<<<B_ROWS / 4, 256, 0, stream>>>(bits, W2, b2, out);
    } else {
        uint32_t* bits = (uint32_t*)ws;
        dim3 g1(H_DIM / BN, B_ROWS / BM);
        snn_fc1<<<g1, 256, 0, stream>>>(x, W1, b1, bits);
        snn_fc2w<<<B_ROWS / 4, 256, 0, stream>>>(bits, W2, b2, out);
    }
}

// Round 9
// 408.933 us; speedup vs baseline: 3.3768x; 1.1217x over previous
//
#include <hip/hip_runtime.h>
#include <cstdint>
#include <cstddef>

typedef __attribute__((ext_vector_type(8))) _Float16 f16x8;
typedef __attribute__((ext_vector_type(4))) float f32x4;

#define B_ROWS 16384
#define K_DIM  1024
#define H_DIM  4096
#define O_DIM  4
#define NT     32              // K_DIM / 32 K-tiles
#define MARGIN 3e-3f
#define STASH_CAP 2048         // flags/block ~Poisson(24); 85x headroom

// ws layout (bytes)
#define OFF_XH   ((size_t)0)                 // 16384*1024*2 = 33554432
#define OFF_WH   ((size_t)33554432)          // 4096*1024*2  =  8388608
#define OFF_BITS ((size_t)41943040)          // 16384*128*4  =  8388608
#define WS_NEED  ((size_t)50331648)

#define GLD16(g, l) __builtin_amdgcn_global_load_lds(                         \
    (const __attribute__((address_space(1))) void*)(g),                       \
    (__attribute__((address_space(3))) void*)(l), 16, 0, 0)

// ---------------------------------------------------------------------------
// split: f32 -> f16 (RTN) for x and W1, fused.
// ---------------------------------------------------------------------------
__global__ __launch_bounds__(256) void split_f16(
    const float* __restrict__ x, const float* __restrict__ W1,
    _Float16* __restrict__ Xh, _Float16* __restrict__ Wh)
{
    const int NX8 = (B_ROWS * K_DIM) / 8;
    const int NW8 = (H_DIM * K_DIM) / 8;
    const int stride = gridDim.x * blockDim.x;
    for (int i = blockIdx.x * blockDim.x + threadIdx.x; i < NX8 + NW8; i += stride) {
        const float* src; _Float16* dst; int j;
        if (i < NX8) { src = x; dst = Xh; j = i; }
        else         { src = W1; dst = Wh; j = i - NX8; }
        const float4 f0 = reinterpret_cast<const float4*>(src)[2 * j];
        const float4 f1 = reinterpret_cast<const float4*>(src)[2 * j + 1];
        f16x8 h;
        h[0] = (_Float16)f0.x; h[1] = (_Float16)f0.y;
        h[2] = (_Float16)f0.z; h[3] = (_Float16)f0.w;
        h[4] = (_Float16)f1.x; h[5] = (_Float16)f1.y;
        h[6] = (_Float16)f1.z; h[7] = (_Float16)f1.w;
        reinterpret_cast<f16x8*>(dst)[j] = h;
    }
}

// ---------------------------------------------------------------------------
// fc1: f16 MFMA GEMM (r8 loop, conflict-free swizzle) + FUSED exact refine.
// Epilogue: ballot words -> LDS bitbuf, near-boundary flags -> LDS stash,
// in-block wave-parallel f64 re-verify fixing bits via LDS atomics
// (coherent by construction), then one coalesced store per word.
// ---------------------------------------------------------------------------
__global__ __launch_bounds__(256) void fc1_f16(
    const _Float16* __restrict__ Xh, const _Float16* __restrict__ Wh,
    const float* __restrict__ xf, const float* __restrict__ w1f,
    const float* __restrict__ b1, uint32_t* __restrict__ bits)
{
    __shared__ __align__(16) _Float16 As[2][128 * 32];
    __shared__ __align__(16) _Float16 Bs[2][128 * 32];
    __shared__ uint32_t scnt;

    const int tid  = threadIdx.x;
    const int lane = tid & 63;
    const int w    = tid >> 6;                 // wave 0..3
    const int m0   = blockIdx.y * 128;
    const int n0   = blockIdx.x * 128;

    // staging: lane covers row w*16 + (lane>>2) (+64); 16B chunk = (lane&3)
    // XOR'd with (row>>1)&3 on the GLOBAL side (LDS dest linear, rule 21).
    const int   srow   = w * 16 + (lane >> 2);
    const int   schunk = (((lane & 3) ^ ((srow >> 1) & 3)) << 3);  // halfs
    const size_t gA0 = (size_t)(m0 + srow) * K_DIM + schunk;
    const size_t gA1 = (size_t)(m0 + srow + 64) * K_DIM + schunk;
    const size_t gB0 = (size_t)(n0 + srow) * K_DIM + schunk;
    const size_t gB1 = (size_t)(n0 + srow + 64) * K_DIM + schunk;

    auto stage = [&](int buf, int t) {
        const int k0 = t * 32;
        GLD16(Xh + gA0 + k0, &As[buf][w * 512]);
        GLD16(Xh + gA1 + k0, &As[buf][2048 + w * 512]);
        GLD16(Wh + gB0 + k0, &Bs[buf][w * 512]);
        GLD16(Wh + gB1 + k0, &Bs[buf][2048 + w * 512]);
    };

    const int wr   = (w >> 1) * 64;            // wave row offset
    const int wc   = (w & 1) * 64;             // wave col offset
    const int frow = lane & 15;
    const int rsw  = (((lane >> 4) ^ ((frow >> 1) & 3)) << 3);     // halfs

    f32x4 acc[4][4];
#pragma unroll
    for (int i = 0; i < 4; ++i)
#pragma unroll
        for (int j = 0; j < 4; ++j)
            acc[i][j] = (f32x4){0.f, 0.f, 0.f, 0.f};

    stage(0, 0);
    int buf = 0;
    for (int t = 0; t < NT; ++t) {
        __syncthreads();                       // drains stage(t)
        if (t + 1 < NT) stage(buf ^ 1, t + 1);
        f16x8 a[4], b[4];
#pragma unroll
        for (int mi = 0; mi < 4; ++mi)
            a[mi] = *reinterpret_cast<const f16x8*>(
                &As[buf][(wr + mi * 16 + frow) * 32 + rsw]);
#pragma unroll
        for (int nj = 0; nj < 4; ++nj)
            b[nj] = *reinterpret_cast<const f16x8*>(
                &Bs[buf][(wc + nj * 16 + frow) * 32 + rsw]);
#pragma unroll
        for (int mi = 0; mi < 4; ++mi)
#pragma unroll
            for (int nj = 0; nj < 4; ++nj)
                acc[mi][nj] = __builtin_amdgcn_mfma_f32_16x16x32_f16(
                    a[mi], b[nj], acc[mi][nj], 0, 0, 0);
        buf ^= 1;
    }

    // ---- epilogue pass 1: ballot words -> LDS bitbuf, flags -> LDS stash ----
    __syncthreads();                           // staged data dead; reuse LDS
    uint32_t* stash  = (uint32_t*)&As[0][0];   // up to STASH_CAP entries
    uint32_t* bitbuf = (uint32_t*)&Bs[0][0];   // 128 rows x 4 words = 2 KB
    if (tid == 0) scnt = 0u;
    __syncthreads();

    float bcol[4];
#pragma unroll
    for (int nj = 0; nj < 4; ++nj) bcol[nj] = b1[n0 + wc + nj * 16 + frow];

    const int g = lane >> 4;
#pragma unroll
    for (int mi = 0; mi < 4; ++mi) {
#pragma unroll
        for (int r = 0; r < 4; ++r) {
            unsigned long long bj[4];
#pragma unroll
            for (int nj = 0; nj < 4; ++nj) {
                const float cur = acc[mi][nj][r] + bcol[nj];
                bj[nj] = __ballot(cur > 1.0f);
                if (fabsf(cur - 1.0f) < MARGIN) {
                    const uint32_t enc =
                        ((uint32_t)(wr + mi * 16 + g * 4 + r) << 7)
                      | (uint32_t)(wc + nj * 16 + frow);
                    uint32_t ix = atomicAdd(&scnt, 1u);
                    if (ix < STASH_CAP) stash[ix] = enc;
                    // overflow (structurally ~impossible at 85x mean): keep
                    // the f16 decision for the excess element.
                }
            }
            if (frow == 0) {
                const int row_l = wr + mi * 16 + g * 4 + r;
                const uint32_t w0 =
                    (uint32_t)((bj[0] >> (g * 16)) & 0xFFFFull) |
                    ((uint32_t)((bj[1] >> (g * 16)) & 0xFFFFull) << 16);
                const uint32_t w1 =
                    (uint32_t)((bj[2] >> (g * 16)) & 0xFFFFull) |
                    ((uint32_t)((bj[3] >> (g * 16)) & 0xFFFFull) << 16);
                uint2 v; v.x = w0; v.y = w1;
                *reinterpret_cast<uint2*>(&bitbuf[row_l * 4 + (wc >> 5)]) = v;
            }
        }
    }
    __syncthreads();

    // ---- epilogue pass 2: in-block exact f64 refine (wave per flag) ----
    const uint32_t nf = (scnt < STASH_CAP) ? scnt : STASH_CAP;
    for (uint32_t f = (uint32_t)w; f < nf; f += 4) {
        const uint32_t e = stash[f];
        const int row_l = (int)(e >> 7), col_l = (int)(e & 127);
        const float4* xr = (const float4*)(xf  + (size_t)(m0 + row_l) * K_DIM);
        const float4* wr2 = (const float4*)(w1f + (size_t)(n0 + col_l) * K_DIM);
        double s = 0.0;
#pragma unroll
        for (int i = 0; i < 4; ++i) {
            const float4 xa = xr[lane + i * 64];
            const float4 wa = wr2[lane + i * 64];
            s = fma((double)xa.x, (double)wa.x, s);
            s = fma((double)xa.y, (double)wa.y, s);
            s = fma((double)xa.z, (double)wa.z, s);
            s = fma((double)xa.w, (double)wa.w, s);
        }
        for (int off = 32; off; off >>= 1) s += __shfl_down(s, off, 64);
        if (lane == 0) {
            const double cur = s + (double)b1[n0 + col_l];
            uint32_t* word = &bitbuf[row_l * 4 + (col_l >> 5)];
            const uint32_t mask = 1u << (col_l & 31);
            if (cur > 1.0) atomicOr(word, mask);
            else           atomicAnd(word, ~mask);
        }
    }
    __syncthreads();

    // ---- epilogue pass 3: coalesced store, each word exactly once ----
    if (tid < 128) {
        const uint4 v = *reinterpret_cast<const uint4*>(&bitbuf[tid * 4]);
        *reinterpret_cast<uint4*>(
            &bits[(size_t)(m0 + tid) * 128 + (n0 >> 5)]) = v;
    }
}

// ---------------------------------------------------------------------------
// fc2: one wave per batch row; f64 exact select-add over spike bits.
// ---------------------------------------------------------------------------
__global__ __launch_bounds__(256) void snn_fc2w(
    const uint32_t* __restrict__ bits, const float* __restrict__ W2,
    const float* __restrict__ b2, float* __restrict__ out)
{
    const int lane = threadIdx.x & 63;
    const int row  = (blockIdx.x << 2) + (threadIdx.x >> 6);
    const uint32_t w0 = bits[(size_t)row * 128 + 2 * lane];
    const uint32_t w1 = bits[(size_t)row * 128 + 2 * lane + 1];
    double acc[4];
#pragma unroll
    for (int o = 0; o < 4; ++o) {
        const float4* wrow = (const float4*)(W2 + (size_t)o * H_DIM + lane * 64);
        double a = 0.0;
#pragma unroll
        for (int q = 0; q < 16; ++q) {
            const float4 v = wrow[q];
            const uint32_t word = (q < 8) ? w0 : w1;
            const int bit = (4 * q) & 31;
            if ((word >> bit)       & 1u) a += (double)v.x;
            if ((word >> (bit + 1)) & 1u) a += (double)v.y;
            if ((word >> (bit + 2)) & 1u) a += (double)v.z;
            if ((word >> (bit + 3)) & 1u) a += (double)v.w;
        }
        acc[o] = a;
    }
#pragma unroll
    for (int off = 32; off; off >>= 1)
#pragma unroll
        for (int o = 0; o < 4; ++o) acc[o] += __shfl_down(acc[o], off, 64);
    if (lane == 0) {
#pragma unroll
        for (int o = 0; o < 4; ++o) {
            const double cur = acc[o] + (double)b2[o];
            out[row * 4 + o] = (float)cur;
            out[B_ROWS * O_DIM + row * 4 + o] = (cur > 1.0) ? 1.0f : 0.0f;
        }
    }
}

// ---------------------------------------------------------------------------
// Fallback exact-f64 fc1 (round-1 kernel) for small ws_size
// ---------------------------------------------------------------------------
#define BM 64
#define BN 64
#define BK 32
__global__ __launch_bounds__(256) void snn_fc1(
    const float* __restrict__ x, const float* __restrict__ W1,
    const float* __restrict__ b1, uint32_t* __restrict__ spk_bits)
{
    __shared__ float As[BK][68];
    __shared__ float Bs[BK][68];
    __shared__ uint32_t bitbuf[BM][BN / 32];

    const int tid = threadIdx.x;
    const int m0 = blockIdx.y * BM;
    const int n0 = blockIdx.x * BN;
    const int rm = tid & 15, cn = tid >> 4;
    const int mf = 4 * rm, nf = 4 * cn;

    double acc[4][4];
#pragma unroll
    for (int i = 0; i < 4; ++i)
#pragma unroll
        for (int j = 0; j < 4; ++j) acc[i][j] = 0.0;

    const int sm = tid >> 3, skq = tid & 7;
    for (int kt = 0; kt < K_DIM / BK; ++kt) {
        const int k0 = kt * BK;
#pragma unroll
        for (int s = 0; s < 2; ++s) {
            const int m = sm + 32 * s;
            const float4 av = *reinterpret_cast<const float4*>(
                x + (size_t)(m0 + m) * K_DIM + k0 + 4 * skq);
            As[4 * skq + 0][m] = av.x; As[4 * skq + 1][m] = av.y;
            As[4 * skq + 2][m] = av.z; As[4 * skq + 3][m] = av.w;
            const float4 bv = *reinterpret_cast<const float4*>(
                W1 + (size_t)(n0 + m) * K_DIM + k0 + 4 * skq);
            Bs[4 * skq + 0][m] = bv.x; Bs[4 * skq + 1][m] = bv.y;
            Bs[4 * skq + 2][m] = bv.z; Bs[4 * skq + 3][m] = bv.w;
        }
        __syncthreads();
#pragma unroll
        for (int k = 0; k < BK; ++k) {
            const float4 af = *reinterpret_cast<const float4*>(&As[k][mf]);
            const float4 bf = *reinterpret_cast<const float4*>(&Bs[k][nf]);
            const double a0 = af.x, a1 = af.y, a2 = af.z, a3 = af.w;
            const double b0 = bf.x, b1v = bf.y, b2v = bf.z, b3 = bf.w;
            acc[0][0] = fma(a0, b0, acc[0][0]);  acc[0][1] = fma(a0, b1v, acc[0][1]);
            acc[0][2] = fma(a0, b2v, acc[0][2]); acc[0][3] = fma(a0, b3, acc[0][3]);
            acc[1][0] = fma(a1, b0, acc[1][0]);  acc[1][1] = fma(a1, b1v, acc[1][1]);
            acc[1][2] = fma(a1, b2v, acc[1][2]); acc[1][3] = fma(a1, b3, acc[1][3]);
            acc[2][0] = fma(a2, b0, acc[2][0]);  acc[2][1] = fma(a2, b1v, acc[2][1]);
            acc[2][2] = fma(a2, b2v, acc[2][2]); acc[2][3] = fma(a2, b3, acc[2][3]);
            acc[3][0] = fma(a3, b0, acc[3][0]);  acc[3][1] = fma(a3, b1v, acc[3][1]);
            acc[3][2] = fma(a3, b2v, acc[3][2]); acc[3][3] = fma(a3, b3, acc[3][3]);
        }
        __syncthreads();
    }

    if (tid < BM * (BN / 32)) bitbuf[tid >> 1][tid & 1] = 0u;
    __syncthreads();
#pragma unroll
    for (int j = 0; j < 4; ++j) {
        const int n = nf + j;
        const double bias = (double)b1[n0 + n];
        const int wd = n >> 5, bit = n & 31;
#pragma unroll
        for (int i = 0; i < 4; ++i) {
            const double cur = acc[i][j] + bias;
            if (cur > 1.0) atomicOr(&bitbuf[mf + i][wd], 1u << bit);
        }
    }
    __syncthreads();
    if (tid < 128) {
        const int r = tid >> 1, wd = tid & 1;
        spk_bits[(size_t)(m0 + r) * (H_DIM / 32) + (n0 >> 5) + wd] = bitbuf[r][wd];
    }
}

// ---------------------------------------------------------------------------
extern "C" void kernel_launch(void* const* d_in, const int* in_sizes, int n_in,
                              void* d_out, int out_size, void* d_ws, size_t ws_size,
                              hipStream_t stream) {
    const float* x  = (const float*)d_in[0];
    const float* W1 = (const float*)d_in[1];
    const float* b1 = (const float*)d_in[2];
    const float* W2 = (const float*)d_in[3];
    const float* b2 = (const float*)d_in[4];
    float* out = (float*)d_out;
    char* ws = (char*)d_ws;

    if (ws_size >= WS_NEED) {
        _Float16* Xh   = (_Float16*)(ws + OFF_XH);
        _Float16* Wh   = (_Float16*)(ws + OFF_WH);
        uint32_t* bits = (uint32_t*)(ws + OFF_BITS);

        split_f16<<<2048, 256, 0, stream>>>(x, W1, Xh, Wh);
        fc1_f16<<<dim3(H_DIM / 128, B_ROWS / 128), 256, 0, stream>>>(
            Xh, Wh, x, W1, b1, bits);
        snn_fc2w<<<B_ROWS / 4, 256, 0, stream>>>(bits, W2, b2, out);
    } else {
        uint32_t* bits = (uint32_t*)ws;
        dim3 g1(H_DIM / BN, B_ROWS / BM);
        snn_fc1<<<g1, 256, 0, stream>>>(x, W1, b1, bits);
        snn_fc2w<<<B_ROWS / 4, 256, 0, stream>>>(bits, W2, b2, out);
    }
}

// Round 10
// 394.149 us; speedup vs baseline: 3.5035x; 1.0375x over previous
//
#include <hip/hip_runtime.h>
#include <cstdint>
#include <cstddef>

typedef __attribute__((ext_vector_type(8))) _Float16 f16x8;
typedef __attribute__((ext_vector_type(4))) float f32x4;

#define B_ROWS 16384
#define K_DIM  1024
#define H_DIM  4096
#define O_DIM  4
#define NT     32              // K_DIM / 32 K-tiles
#define MARGIN 3e-3f
#define STASH_CAP 2048         // flags/block ~Poisson(24); 85x headroom

// ws layout (bytes)
#define OFF_XH   ((size_t)0)                 // 16384*1024*2 = 33554432
#define OFF_WH   ((size_t)33554432)          // 4096*1024*2  =  8388608
#define OFF_BITS ((size_t)41943040)          // 16384*128*4  =  8388608
#define WS_NEED  ((size_t)50331648)

#define GLD16(g, l) __builtin_amdgcn_global_load_lds(                         \
    (const __attribute__((address_space(1))) void*)(g),                       \
    (__attribute__((address_space(3))) void*)(l), 16, 0, 0)

// ---------------------------------------------------------------------------
// split: f32 -> f16 (RTN) for x and W1, fused.
// ---------------------------------------------------------------------------
__global__ __launch_bounds__(256) void split_f16(
    const float* __restrict__ x, const float* __restrict__ W1,
    _Float16* __restrict__ Xh, _Float16* __restrict__ Wh)
{
    const int NX8 = (B_ROWS * K_DIM) / 8;
    const int NW8 = (H_DIM * K_DIM) / 8;
    const int stride = gridDim.x * blockDim.x;
    for (int i = blockIdx.x * blockDim.x + threadIdx.x; i < NX8 + NW8; i += stride) {
        const float* src; _Float16* dst; int j;
        if (i < NX8) { src = x; dst = Xh; j = i; }
        else         { src = W1; dst = Wh; j = i - NX8; }
        const float4 f0 = reinterpret_cast<const float4*>(src)[2 * j];
        const float4 f1 = reinterpret_cast<const float4*>(src)[2 * j + 1];
        f16x8 h;
        h[0] = (_Float16)f0.x; h[1] = (_Float16)f0.y;
        h[2] = (_Float16)f0.z; h[3] = (_Float16)f0.w;
        h[4] = (_Float16)f1.x; h[5] = (_Float16)f1.y;
        h[6] = (_Float16)f1.z; h[7] = (_Float16)f1.w;
        reinterpret_cast<f16x8*>(dst)[j] = h;
    }
}

// ---------------------------------------------------------------------------
// fc1: f16 MFMA GEMM, 128x128 tile, BK=32, 4 waves, 3-deep LDS ring with
// counted vmcnt(4) (T4) — stage tile t+2 while computing tile t; one raw
// s_barrier per iteration; NO sched_barrier (r3/m141 lesson). Conflict-free
// chunk-XOR swizzle (r8). FUSED exact f64 refine epilogue (r9).
// ---------------------------------------------------------------------------
__global__ __launch_bounds__(256) void fc1_f16(
    const _Float16* __restrict__ Xh, const _Float16* __restrict__ Wh,
    const float* __restrict__ xf, const float* __restrict__ w1f,
    const float* __restrict__ b1, uint32_t* __restrict__ bits)
{
    __shared__ __align__(16) _Float16 As[3][128 * 32];   // 24 KB
    __shared__ __align__(16) _Float16 Bs[3][128 * 32];   // 24 KB
    __shared__ uint32_t scnt;

    const int tid  = threadIdx.x;
    const int lane = tid & 63;
    const int w    = tid >> 6;                 // wave 0..3
    const int m0   = blockIdx.y * 128;
    const int n0   = blockIdx.x * 128;

    // staging: lane covers row w*16 + (lane>>2) (+64); 16B chunk = (lane&3)
    // XOR'd with (row>>1)&3 on the GLOBAL side (LDS dest linear, rule 21).
    const int   srow   = w * 16 + (lane >> 2);
    const int   schunk = (((lane & 3) ^ ((srow >> 1) & 3)) << 3);  // halfs
    const size_t gA0 = (size_t)(m0 + srow) * K_DIM + schunk;
    const size_t gA1 = (size_t)(m0 + srow + 64) * K_DIM + schunk;
    const size_t gB0 = (size_t)(n0 + srow) * K_DIM + schunk;
    const size_t gB1 = (size_t)(n0 + srow + 64) * K_DIM + schunk;

    auto stage = [&](int rb, int t) {
        const int k0 = t * 32;
        GLD16(Xh + gA0 + k0, &As[rb][w * 512]);
        GLD16(Xh + gA1 + k0, &As[rb][2048 + w * 512]);
        GLD16(Wh + gB0 + k0, &Bs[rb][w * 512]);
        GLD16(Wh + gB1 + k0, &Bs[rb][2048 + w * 512]);
    };

    const int wr   = (w >> 1) * 64;            // wave row offset
    const int wc   = (w & 1) * 64;             // wave col offset
    const int frow = lane & 15;
    const int rsw  = (((lane >> 4) ^ ((frow >> 1) & 3)) << 3);     // halfs

    f32x4 acc[4][4];
#pragma unroll
    for (int i = 0; i < 4; ++i)
#pragma unroll
        for (int j = 0; j < 4; ++j)
            acc[i][j] = (f32x4){0.f, 0.f, 0.f, 0.f};

    // prologue: tiles 0,1 in flight; wait tile 0 (4 newest = tile 1 stay out)
    stage(0, 0);
    stage(1, 1);
    asm volatile("s_waitcnt vmcnt(4)" ::: "memory");
    __builtin_amdgcn_s_barrier();

    int cur = 0, s2 = 2;
    for (int t = 0; t < NT; ++t) {
        if (t + 2 < NT) stage(s2, t + 2);      // issue ahead (T3 ordering)
        f16x8 a[4], b[4];
#pragma unroll
        for (int mi = 0; mi < 4; ++mi)
            a[mi] = *reinterpret_cast<const f16x8*>(
                &As[cur][(wr + mi * 16 + frow) * 32 + rsw]);
#pragma unroll
        for (int nj = 0; nj < 4; ++nj)
            b[nj] = *reinterpret_cast<const f16x8*>(
                &Bs[cur][(wc + nj * 16 + frow) * 32 + rsw]);
        __builtin_amdgcn_s_setprio(1);
#pragma unroll
        for (int mi = 0; mi < 4; ++mi)
#pragma unroll
            for (int nj = 0; nj < 4; ++nj)
                acc[mi][nj] = __builtin_amdgcn_mfma_f32_16x16x32_f16(
                    a[mi], b[nj], acc[mi][nj], 0, 0, 0);
        __builtin_amdgcn_s_setprio(0);
        // drain this tile's ds_reads (WAR safety for slot reuse), then wait
        // tile t+1 landed: 4 newest (tile t+2's loads) may stay in flight.
        asm volatile("s_waitcnt lgkmcnt(0)" ::: "memory");
        if (t + 2 < NT) { asm volatile("s_waitcnt vmcnt(4)" ::: "memory"); }
        else            { asm volatile("s_waitcnt vmcnt(0)" ::: "memory"); }
        __builtin_amdgcn_s_barrier();
        cur = (cur == 2) ? 0 : cur + 1;
        s2  = (s2  == 2) ? 0 : s2  + 1;
    }

    // ---- epilogue pass 1: ballot words -> LDS bitbuf, flags -> LDS stash ----
    __syncthreads();                           // staged data dead; reuse LDS
    uint32_t* stash  = (uint32_t*)&As[0][0];   // up to STASH_CAP entries
    uint32_t* bitbuf = (uint32_t*)&Bs[0][0];   // 128 rows x 4 words = 2 KB
    if (tid == 0) scnt = 0u;
    __syncthreads();

    float bcol[4];
#pragma unroll
    for (int nj = 0; nj < 4; ++nj) bcol[nj] = b1[n0 + wc + nj * 16 + frow];

    const int g = lane >> 4;
#pragma unroll
    for (int mi = 0; mi < 4; ++mi) {
#pragma unroll
        for (int r = 0; r < 4; ++r) {
            unsigned long long bj[4];
#pragma unroll
            for (int nj = 0; nj < 4; ++nj) {
                const float cur_v = acc[mi][nj][r] + bcol[nj];
                bj[nj] = __ballot(cur_v > 1.0f);
                if (fabsf(cur_v - 1.0f) < MARGIN) {
                    const uint32_t enc =
                        ((uint32_t)(wr + mi * 16 + g * 4 + r) << 7)
                      | (uint32_t)(wc + nj * 16 + frow);
                    uint32_t ix = atomicAdd(&scnt, 1u);
                    if (ix < STASH_CAP) stash[ix] = enc;
                }
            }
            if (frow == 0) {
                const int row_l = wr + mi * 16 + g * 4 + r;
                const uint32_t w0 =
                    (uint32_t)((bj[0] >> (g * 16)) & 0xFFFFull) |
                    ((uint32_t)((bj[1] >> (g * 16)) & 0xFFFFull) << 16);
                const uint32_t w1 =
                    (uint32_t)((bj[2] >> (g * 16)) & 0xFFFFull) |
                    ((uint32_t)((bj[3] >> (g * 16)) & 0xFFFFull) << 16);
                uint2 v; v.x = w0; v.y = w1;
                *reinterpret_cast<uint2*>(&bitbuf[row_l * 4 + (wc >> 5)]) = v;
            }
        }
    }
    __syncthreads();

    // ---- epilogue pass 2: in-block exact f64 refine (wave per flag) ----
    const uint32_t nf = (scnt < STASH_CAP) ? scnt : STASH_CAP;
    for (uint32_t f = (uint32_t)w; f < nf; f += 4) {
        const uint32_t e = stash[f];
        const int row_l = (int)(e >> 7), col_l = (int)(e & 127);
        const float4* xr  = (const float4*)(xf  + (size_t)(m0 + row_l) * K_DIM);
        const float4* wr2 = (const float4*)(w1f + (size_t)(n0 + col_l) * K_DIM);
        double s = 0.0;
#pragma unroll
        for (int i = 0; i < 4; ++i) {
            const float4 xa = xr[lane + i * 64];
            const float4 wa = wr2[lane + i * 64];
            s = fma((double)xa.x, (double)wa.x, s);
            s = fma((double)xa.y, (double)wa.y, s);
            s = fma((double)xa.z, (double)wa.z, s);
            s = fma((double)xa.w, (double)wa.w, s);
        }
        for (int off = 32; off; off >>= 1) s += __shfl_down(s, off, 64);
        if (lane == 0) {
            const double cur_v = s + (double)b1[n0 + col_l];
            uint32_t* word = &bitbuf[row_l * 4 + (col_l >> 5)];
            const uint32_t mask = 1u << (col_l & 31);
            if (cur_v > 1.0) atomicOr(word, mask);
            else             atomicAnd(word, ~mask);
        }
    }
    __syncthreads();

    // ---- epilogue pass 3: coalesced store, each word exactly once ----
    if (tid < 128) {
        const uint4 v = *reinterpret_cast<const uint4*>(&bitbuf[tid * 4]);
        *reinterpret_cast<uint4*>(
            &bits[(size_t)(m0 + tid) * 128 + (n0 >> 5)]) = v;
    }
}

// ---------------------------------------------------------------------------
// fc2: one wave per batch row; f64 exact select-add over spike bits.
// ---------------------------------------------------------------------------
__global__ __launch_bounds__(256) void snn_fc2w(
    const uint32_t* __restrict__ bits, const float* __restrict__ W2,
    const float* __restrict__ b2, float* __restrict__ out)
{
    const int lane = threadIdx.x & 63;
    const int row  = (blockIdx.x << 2) + (threadIdx.x >> 6);
    const uint32_t w0 = bits[(size_t)row * 128 + 2 * lane];
    const uint32_t w1 = bits[(size_t)row * 128 + 2 * lane + 1];
    double acc[4];
#pragma unroll
    for (int o = 0; o < 4; ++o) {
        const float4* wrow = (const float4*)(W2 + (size_t)o * H_DIM + lane * 64);
        double a = 0.0;
#pragma unroll
        for (int q = 0; q < 16; ++q) {
            const float4 v = wrow[q];
            const uint32_t word = (q < 8) ? w0 : w1;
            const int bit = (4 * q) & 31;
            if ((word >> bit)       & 1u) a += (double)v.x;
            if ((word >> (bit + 1)) & 1u) a += (double)v.y;
            if ((word >> (bit + 2)) & 1u) a += (double)v.z;
            if ((word >> (bit + 3)) & 1u) a += (double)v.w;
        }
        acc[o] = a;
    }
#pragma unroll
    for (int off = 32; off; off >>= 1)
#pragma unroll
        for (int o = 0; o < 4; ++o) acc[o] += __shfl_down(acc[o], off, 64);
    if (lane == 0) {
#pragma unroll
        for (int o = 0; o < 4; ++o) {
            const double cur = acc[o] + (double)b2[o];
            out[row * 4 + o] = (float)cur;
            out[B_ROWS * O_DIM + row * 4 + o] = (cur > 1.0) ? 1.0f : 0.0f;
        }
    }
}

// ---------------------------------------------------------------------------
// Fallback exact-f64 fc1 (round-1 kernel) for small ws_size
// ---------------------------------------------------------------------------
#define BM 64
#define BN 64
#define BK 32
__global__ __launch_bounds__(256) void snn_fc1(
    const float* __restrict__ x, const float* __restrict__ W1,
    const float* __restrict__ b1, uint32_t* __restrict__ spk_bits)
{
    __shared__ float As[BK][68];
    __shared__ float Bs[BK][68];
    __shared__ uint32_t bitbuf[BM][BN / 32];

    const int tid = threadIdx.x;
    const int m0 = blockIdx.y * BM;
    const int n0 = blockIdx.x * BN;
    const int rm = tid & 15, cn = tid >> 4;
    const int mf = 4 * rm, nf = 4 * cn;

    double acc[4][4];
#pragma unroll
    for (int i = 0; i < 4; ++i)
#pragma unroll
        for (int j = 0; j < 4; ++j) acc[i][j] = 0.0;

    const int sm = tid >> 3, skq = tid & 7;
    for (int kt = 0; kt < K_DIM / BK; ++kt) {
        const int k0 = kt * BK;
#pragma unroll
        for (int s = 0; s < 2; ++s) {
            const int m = sm + 32 * s;
            const float4 av = *reinterpret_cast<const float4*>(
                x + (size_t)(m0 + m) * K_DIM + k0 + 4 * skq);
            As[4 * skq + 0][m] = av.x; As[4 * skq + 1][m] = av.y;
            As[4 * skq + 2][m] = av.z; As[4 * skq + 3][m] = av.w;
            const float4 bv = *reinterpret_cast<const float4*>(
                W1 + (size_t)(n0 + m) * K_DIM + k0 + 4 * skq);
            Bs[4 * skq + 0][m] = bv.x; Bs[4 * skq + 1][m] = bv.y;
            Bs[4 * skq + 2][m] = bv.z; Bs[4 * skq + 3][m] = bv.w;
        }
        __syncthreads();
#pragma unroll
        for (int k = 0; k < BK; ++k) {
            const float4 af = *reinterpret_cast<const float4*>(&As[k][mf]);
            const float4 bf = *reinterpret_cast<const float4*>(&Bs[k][nf]);
            const double a0 = af.x, a1 = af.y, a2 = af.z, a3 = af.w;
            const double b0 = bf.x, b1v = bf.y, b2v = bf.z, b3 = bf.w;
            acc[0][0] = fma(a0, b0, acc[0][0]);  acc[0][1] = fma(a0, b1v, acc[0][1]);
            acc[0][2] = fma(a0, b2v, acc[0][2]); acc[0][3] = fma(a0, b3, acc[0][3]);
            acc[1][0] = fma(a1, b0, acc[1][0]);  acc[1][1] = fma(a1, b1v, acc[1][1]);
            acc[1][2] = fma(a1, b2v, acc[1][2]); acc[1][3] = fma(a1, b3, acc[1][3]);
            acc[2][0] = fma(a2, b0, acc[2][0]);  acc[2][1] = fma(a2, b1v, acc[2][1]);
            acc[2][2] = fma(a2, b2v, acc[2][2]); acc[2][3] = fma(a2, b3, acc[2][3]);
            acc[3][0] = fma(a3, b0, acc[3][0]);  acc[3][1] = fma(a3, b1v, acc[3][1]);
            acc[3][2] = fma(a3, b2v, acc[3][2]); acc[3][3] = fma(a3, b3, acc[3][3]);
        }
        __syncthreads();
    }

    if (tid < BM * (BN / 32)) bitbuf[tid >> 1][tid & 1] = 0u;
    __syncthreads();
#pragma unroll
    for (int j = 0; j < 4; ++j) {
        const int n = nf + j;
        const double bias = (double)b1[n0 + n];
        const int wd = n >> 5, bit = n & 31;
#pragma unroll
        for (int i = 0; i < 4; ++i) {
            const double cur = acc[i][j] + bias;
            if (cur > 1.0) atomicOr(&bitbuf[mf + i][wd], 1u << bit);
        }
    }
    __syncthreads();
    if (tid < 128) {
        const int r = tid >> 1, wd = tid & 1;
        spk_bits[(size_t)(m0 + r) * (H_DIM / 32) + (n0 >> 5) + wd] = bitbuf[r][wd];
    }
}

// ---------------------------------------------------------------------------
extern "C" void kernel_launch(void* const* d_in, const int* in_sizes, int n_in,
                              void* d_out, int out_size, void* d_ws, size_t ws_size,
                              hipStream_t stream) {
    const float* x  = (const float*)d_in[0];
    const float* W1 = (const float*)d_in[1];
    const float* b1 = (const float*)d_in[2];
    const float* W2 = (const float*)d_in[3];
    const float* b2 = (const float*)d_in[4];
    float* out = (float*)d_out;
    char* ws = (char*)d_ws;

    if (ws_size >= WS_NEED) {
        _Float16* Xh   = (_Float16*)(ws + OFF_XH);
        _Float16* Wh   = (_Float16*)(ws + OFF_WH);
        uint32_t* bits = (uint32_t*)(ws + OFF_BITS);

        split_f16<<<2048, 256, 0, stream>>>(x, W1, Xh, Wh);
        fc1_f16<<<dim3(H_DIM / 128, B_ROWS / 128), 256, 0, stream>>>(
            Xh, Wh, x, W1, b1, bits);
        snn_fc2w<<<B_ROWS / 4, 256, 0, stream>>>(bits, W2, b2, out);
    } else {
        uint32_t* bits = (uint32_t*)ws;
        dim3 g1(H_DIM / BN, B_ROWS / BM);
        snn_fc1<<<g1, 256, 0, stream>>>(x, W1, b1, bits);
        snn_fc2w<<<B_ROWS / 4, 256, 0, stream>>>(bits, W2, b2, out);
    }
}

// Round 11
// 271.119 us; speedup vs baseline: 5.0933x; 1.4538x over previous
//
#include <hip/hip_runtime.h>
#include <cstdint>
#include <cstddef>

typedef __attribute__((ext_vector_type(8))) _Float16 f16x8;
typedef __attribute__((ext_vector_type(4))) float f32x4;

#define B_ROWS 16384
#define K_DIM  1024
#define H_DIM  4096
#define O_DIM  4
#define NT     32              // K_DIM / 32 K-tiles
#define MARGIN 3e-3f
#define STASH_CAP 2048         // flags/block ~Poisson(48); 42x headroom

// ws layout (bytes)
#define OFF_XH   ((size_t)0)                 // 16384*1024*2 = 33554432
#define OFF_WH   ((size_t)33554432)          // 4096*1024*2  =  8388608
#define OFF_BITS ((size_t)41943040)          // 16384*128*4  =  8388608
#define WS_NEED  ((size_t)50331648)

#define GLD16(g, l) __builtin_amdgcn_global_load_lds(                         \
    (const __attribute__((address_space(1))) void*)(g),                       \
    (__attribute__((address_space(3))) void*)(l), 16, 0, 0)

// ---------------------------------------------------------------------------
// split: f32 -> f16 (RTN) for x and W1, fused.
// ---------------------------------------------------------------------------
__global__ __launch_bounds__(256) void split_f16(
    const float* __restrict__ x, const float* __restrict__ W1,
    _Float16* __restrict__ Xh, _Float16* __restrict__ Wh)
{
    const int NX8 = (B_ROWS * K_DIM) / 8;
    const int NW8 = (H_DIM * K_DIM) / 8;
    const int stride = gridDim.x * blockDim.x;
    for (int i = blockIdx.x * blockDim.x + threadIdx.x; i < NX8 + NW8; i += stride) {
        const float* src; _Float16* dst; int j;
        if (i < NX8) { src = x; dst = Xh; j = i; }
        else         { src = W1; dst = Wh; j = i - NX8; }
        const float4 f0 = reinterpret_cast<const float4*>(src)[2 * j];
        const float4 f1 = reinterpret_cast<const float4*>(src)[2 * j + 1];
        f16x8 h;
        h[0] = (_Float16)f0.x; h[1] = (_Float16)f0.y;
        h[2] = (_Float16)f0.z; h[3] = (_Float16)f0.w;
        h[4] = (_Float16)f1.x; h[5] = (_Float16)f1.y;
        h[6] = (_Float16)f1.z; h[7] = (_Float16)f1.w;
        reinterpret_cast<f16x8*>(dst)[j] = h;
    }
}

// ---------------------------------------------------------------------------
// fc1: f16 MFMA GEMM, 256x128 tile, BK=32, 8 waves (4M x 2N), 3-deep LDS
// ring with counted vmcnt(3) — r10 schedule, parameter-scaled. Conflict-free
// chunk-XOR swizzle. FUSED exact f64 refine epilogue.
// ---------------------------------------------------------------------------
__global__ __launch_bounds__(512, 4) void fc1_f16(
    const _Float16* __restrict__ Xh, const _Float16* __restrict__ Wh,
    const float* __restrict__ xf, const float* __restrict__ w1f,
    const float* __restrict__ b1, uint32_t* __restrict__ bits)
{
    __shared__ __align__(16) _Float16 As[3][256 * 32];   // 48 KB
    __shared__ __align__(16) _Float16 Bs[3][128 * 32];   // 24 KB
    __shared__ uint32_t scnt;

    const int tid  = threadIdx.x;
    const int lane = tid & 63;
    const int w    = tid >> 6;                 // wave 0..7
    const int m0   = blockIdx.y * 256;
    const int n0   = blockIdx.x * 128;

    // staging: 8 waves x 16 rows = 128 rows per GLD16 call; A needs 2 calls,
    // B one. 16B chunk = (lane&3) XOR'd with (row>>1)&3 on the GLOBAL side
    // (LDS dest linear, rule 21). (+128 rows keeps the XOR index: 128/2%4==0.)
    const int   srow   = w * 16 + (lane >> 2);            // 0..127
    const int   schunk = (((lane & 3) ^ ((srow >> 1) & 3)) << 3);  // halfs
    const size_t gA0 = (size_t)(m0 + srow) * K_DIM + schunk;
    const size_t gA1 = (size_t)(m0 + 128 + srow) * K_DIM + schunk;
    const size_t gB0 = (size_t)(n0 + srow) * K_DIM + schunk;

    auto stage = [&](int rb, int t) {        // 3 GLD16 per thread
        const int k0 = t * 32;
        GLD16(Xh + gA0 + k0, &As[rb][w * 512]);
        GLD16(Xh + gA1 + k0, &As[rb][4096 + w * 512]);
        GLD16(Wh + gB0 + k0, &Bs[rb][w * 512]);
    };

    const int wr   = (w >> 1) * 64;            // 0,64,128,192  (M group)
    const int wc   = (w & 1) * 64;             // 0,64          (N group)
    const int frow = lane & 15;
    const int rsw  = (((lane >> 4) ^ ((frow >> 1) & 3)) << 3);     // halfs

    f32x4 acc[4][4];
#pragma unroll
    for (int i = 0; i < 4; ++i)
#pragma unroll
        for (int j = 0; j < 4; ++j)
            acc[i][j] = (f32x4){0.f, 0.f, 0.f, 0.f};

    // prologue: tiles 0,1 in flight; wait tile 0 (3 newest = tile 1 stay out)
    stage(0, 0);
    stage(1, 1);
    asm volatile("s_waitcnt vmcnt(3)" ::: "memory");
    __builtin_amdgcn_s_barrier();

    int cur = 0, s2 = 2;
    for (int t = 0; t < NT; ++t) {
        if (t + 2 < NT) stage(s2, t + 2);      // issue ahead
        f16x8 a[4], b[4];
#pragma unroll
        for (int mi = 0; mi < 4; ++mi)
            a[mi] = *reinterpret_cast<const f16x8*>(
                &As[cur][(wr + mi * 16 + frow) * 32 + rsw]);
#pragma unroll
        for (int nj = 0; nj < 4; ++nj)
            b[nj] = *reinterpret_cast<const f16x8*>(
                &Bs[cur][(wc + nj * 16 + frow) * 32 + rsw]);
        __builtin_amdgcn_s_setprio(1);
#pragma unroll
        for (int mi = 0; mi < 4; ++mi)
#pragma unroll
            for (int nj = 0; nj < 4; ++nj)
                acc[mi][nj] = __builtin_amdgcn_mfma_f32_16x16x32_f16(
                    a[mi], b[nj], acc[mi][nj], 0, 0, 0);
        __builtin_amdgcn_s_setprio(0);
        asm volatile("s_waitcnt lgkmcnt(0)" ::: "memory");   // WAR: slot reuse
        if (t + 2 < NT) { asm volatile("s_waitcnt vmcnt(3)" ::: "memory"); }
        else            { asm volatile("s_waitcnt vmcnt(0)" ::: "memory"); }
        __builtin_amdgcn_s_barrier();
        cur = (cur == 2) ? 0 : cur + 1;
        s2  = (s2  == 2) ? 0 : s2  + 1;
    }

    // ---- epilogue pass 1: ballot words -> LDS bitbuf, flags -> LDS stash ----
    __syncthreads();                           // staged data dead; reuse LDS
    uint32_t* stash  = (uint32_t*)&As[0][0];   // up to STASH_CAP entries
    uint32_t* bitbuf = (uint32_t*)&Bs[0][0];   // 256 rows x 4 words = 4 KB
    if (tid == 0) scnt = 0u;
    __syncthreads();

    float bcol[4];
#pragma unroll
    for (int nj = 0; nj < 4; ++nj) bcol[nj] = b1[n0 + wc + nj * 16 + frow];

    const int g = lane >> 4;
#pragma unroll
    for (int mi = 0; mi < 4; ++mi) {
#pragma unroll
        for (int r = 0; r < 4; ++r) {
            unsigned long long bj[4];
#pragma unroll
            for (int nj = 0; nj < 4; ++nj) {
                const float cur_v = acc[mi][nj][r] + bcol[nj];
                bj[nj] = __ballot(cur_v > 1.0f);
                if (fabsf(cur_v - 1.0f) < MARGIN) {
                    const uint32_t enc =
                        ((uint32_t)(wr + mi * 16 + g * 4 + r) << 7)
                      | (uint32_t)(wc + nj * 16 + frow);
                    uint32_t ix = atomicAdd(&scnt, 1u);
                    if (ix < STASH_CAP) stash[ix] = enc;
                }
            }
            if (frow == 0) {
                const int row_l = wr + mi * 16 + g * 4 + r;   // 0..255
                const uint32_t w0 =
                    (uint32_t)((bj[0] >> (g * 16)) & 0xFFFFull) |
                    ((uint32_t)((bj[1] >> (g * 16)) & 0xFFFFull) << 16);
                const uint32_t w1 =
                    (uint32_t)((bj[2] >> (g * 16)) & 0xFFFFull) |
                    ((uint32_t)((bj[3] >> (g * 16)) & 0xFFFFull) << 16);
                uint2 v; v.x = w0; v.y = w1;
                *reinterpret_cast<uint2*>(&bitbuf[row_l * 4 + (wc >> 5)]) = v;
            }
        }
    }
    __syncthreads();

    // ---- epilogue pass 2: in-block exact f64 refine (wave per flag) ----
    const uint32_t nf = (scnt < STASH_CAP) ? scnt : STASH_CAP;
    for (uint32_t f = (uint32_t)w; f < nf; f += 8) {
        const uint32_t e = stash[f];
        const int row_l = (int)(e >> 7), col_l = (int)(e & 127);
        const float4* xr  = (const float4*)(xf  + (size_t)(m0 + row_l) * K_DIM);
        const float4* wr2 = (const float4*)(w1f + (size_t)(n0 + col_l) * K_DIM);
        double s = 0.0;
#pragma unroll
        for (int i = 0; i < 4; ++i) {
            const float4 xa = xr[lane + i * 64];
            const float4 wa = wr2[lane + i * 64];
            s = fma((double)xa.x, (double)wa.x, s);
            s = fma((double)xa.y, (double)wa.y, s);
            s = fma((double)xa.z, (double)wa.z, s);
            s = fma((double)xa.w, (double)wa.w, s);
        }
        for (int off = 32; off; off >>= 1) s += __shfl_down(s, off, 64);
        if (lane == 0) {
            const double cur_v = s + (double)b1[n0 + col_l];
            uint32_t* word = &bitbuf[row_l * 4 + (col_l >> 5)];
            const uint32_t mask = 1u << (col_l & 31);
            if (cur_v > 1.0) atomicOr(word, mask);
            else             atomicAnd(word, ~mask);
        }
    }
    __syncthreads();

    // ---- epilogue pass 3: coalesced store, each word exactly once ----
    if (tid < 256) {
        const uint4 v = *reinterpret_cast<const uint4*>(&bitbuf[tid * 4]);
        *reinterpret_cast<uint4*>(
            &bits[(size_t)(m0 + tid) * 128 + (n0 >> 5)]) = v;
    }
}

// ---------------------------------------------------------------------------
// fc2: one wave per 4 batch rows (W2 loads reused 4x); f64 exact select-add.
// ---------------------------------------------------------------------------
__global__ __launch_bounds__(256) void fc2w4(
    const uint32_t* __restrict__ bits, const float* __restrict__ W2,
    const float* __restrict__ b2, float* __restrict__ out)
{
    const int lane = threadIdx.x & 63;
    const int rb   = (blockIdx.x * 4 + (threadIdx.x >> 6)) * 4;  // row base
    uint32_t w0[4], w1[4];
#pragma unroll
    for (int rr = 0; rr < 4; ++rr) {
        const uint2 v = *reinterpret_cast<const uint2*>(
            &bits[(size_t)(rb + rr) * 128 + 2 * lane]);
        w0[rr] = v.x; w1[rr] = v.y;
    }
    double acc[4][4];                          // [row][output]
#pragma unroll
    for (int rr = 0; rr < 4; ++rr)
#pragma unroll
        for (int o = 0; o < 4; ++o) acc[rr][o] = 0.0;

#pragma unroll
    for (int o = 0; o < 4; ++o) {
        const float4* wrow = (const float4*)(W2 + (size_t)o * H_DIM + lane * 64);
#pragma unroll
        for (int q = 0; q < 16; ++q) {
            const float4 v = wrow[q];
            const int bit = (4 * q) & 31;
#pragma unroll
            for (int rr = 0; rr < 4; ++rr) {
                const uint32_t word = (q < 8) ? w0[rr] : w1[rr];
                if ((word >> bit)       & 1u) acc[rr][o] += (double)v.x;
                if ((word >> (bit + 1)) & 1u) acc[rr][o] += (double)v.y;
                if ((word >> (bit + 2)) & 1u) acc[rr][o] += (double)v.z;
                if ((word >> (bit + 3)) & 1u) acc[rr][o] += (double)v.w;
            }
        }
    }
#pragma unroll
    for (int off = 32; off; off >>= 1)
#pragma unroll
        for (int rr = 0; rr < 4; ++rr)
#pragma unroll
            for (int o = 0; o < 4; ++o)
                acc[rr][o] += __shfl_down(acc[rr][o], off, 64);
    if (lane == 0) {
#pragma unroll
        for (int rr = 0; rr < 4; ++rr)
#pragma unroll
            for (int o = 0; o < 4; ++o) {
                const double cur = acc[rr][o] + (double)b2[o];
                out[(rb + rr) * 4 + o] = (float)cur;
                out[B_ROWS * O_DIM + (rb + rr) * 4 + o] = (cur > 1.0) ? 1.0f : 0.0f;
            }
    }
}

// ---------------------------------------------------------------------------
// Fallback exact-f64 fc1 (round-1 kernel) for small ws_size
// ---------------------------------------------------------------------------
#define BM 64
#define BN 64
#define BK 32
__global__ __launch_bounds__(256) void snn_fc1(
    const float* __restrict__ x, const float* __restrict__ W1,
    const float* __restrict__ b1, uint32_t* __restrict__ spk_bits)
{
    __shared__ float As[BK][68];
    __shared__ float Bs[BK][68];
    __shared__ uint32_t bitbuf[BM][BN / 32];

    const int tid = threadIdx.x;
    const int m0 = blockIdx.y * BM;
    const int n0 = blockIdx.x * BN;
    const int rm = tid & 15, cn = tid >> 4;
    const int mf = 4 * rm, nf = 4 * cn;

    double acc[4][4];
#pragma unroll
    for (int i = 0; i < 4; ++i)
#pragma unroll
        for (int j = 0; j < 4; ++j) acc[i][j] = 0.0;

    const int sm = tid >> 3, skq = tid & 7;
    for (int kt = 0; kt < K_DIM / BK; ++kt) {
        const int k0 = kt * BK;
#pragma unroll
        for (int s = 0; s < 2; ++s) {
            const int m = sm + 32 * s;
            const float4 av = *reinterpret_cast<const float4*>(
                x + (size_t)(m0 + m) * K_DIM + k0 + 4 * skq);
            As[4 * skq + 0][m] = av.x; As[4 * skq + 1][m] = av.y;
            As[4 * skq + 2][m] = av.z; As[4 * skq + 3][m] = av.w;
            const float4 bv = *reinterpret_cast<const float4*>(
                W1 + (size_t)(n0 + m) * K_DIM + k0 + 4 * skq);
            Bs[4 * skq + 0][m] = bv.x; Bs[4 * skq + 1][m] = bv.y;
            Bs[4 * skq + 2][m] = bv.z; Bs[4 * skq + 3][m] = bv.w;
        }
        __syncthreads();
#pragma unroll
        for (int k = 0; k < BK; ++k) {
            const float4 af = *reinterpret_cast<const float4*>(&As[k][mf]);
            const float4 bf = *reinterpret_cast<const float4*>(&Bs[k][nf]);
            const double a0 = af.x, a1 = af.y, a2 = af.z, a3 = af.w;
            const double b0 = bf.x, b1v = bf.y, b2v = bf.z, b3 = bf.w;
            acc[0][0] = fma(a0, b0, acc[0][0]);  acc[0][1] = fma(a0, b1v, acc[0][1]);
            acc[0][2] = fma(a0, b2v, acc[0][2]); acc[0][3] = fma(a0, b3, acc[0][3]);
            acc[1][0] = fma(a1, b0, acc[1][0]);  acc[1][1] = fma(a1, b1v, acc[1][1]);
            acc[1][2] = fma(a1, b2v, acc[1][2]); acc[1][3] = fma(a1, b3, acc[1][3]);
            acc[2][0] = fma(a2, b0, acc[2][0]);  acc[2][1] = fma(a2, b1v, acc[2][1]);
            acc[2][2] = fma(a2, b2v, acc[2][2]); acc[2][3] = fma(a2, b3, acc[2][3]);
            acc[3][0] = fma(a3, b0, acc[3][0]);  acc[3][1] = fma(a3, b1v, acc[3][1]);
            acc[3][2] = fma(a3, b2v, acc[3][2]); acc[3][3] = fma(a3, b3, acc[3][3]);
        }
        __syncthreads();
    }

    if (tid < BM * (BN / 32)) bitbuf[tid >> 1][tid & 1] = 0u;
    __syncthreads();
#pragma unroll
    for (int j = 0; j < 4; ++j) {
        const int n = nf + j;
        const double bias = (double)b1[n0 + n];
        const int wd = n >> 5, bit = n & 31;
#pragma unroll
        for (int i = 0; i < 4; ++i) {
            const double cur = acc[i][j] + bias;
            if (cur > 1.0) atomicOr(&bitbuf[mf + i][wd], 1u << bit);
        }
    }
    __syncthreads();
    if (tid < 128) {
        const int r = tid >> 1, wd = tid & 1;
        spk_bits[(size_t)(m0 + r) * (H_DIM / 32) + (n0 >> 5) + wd] = bitbuf[r][wd];
    }
}

// ---------------------------------------------------------------------------
extern "C" void kernel_launch(void* const* d_in, const int* in_sizes, int n_in,
                              void* d_out, int out_size, void* d_ws, size_t ws_size,
                              hipStream_t stream) {
    const float* x  = (const float*)d_in[0];
    const float* W1 = (const float*)d_in[1];
    const float* b1 = (const float*)d_in[2];
    const float* W2 = (const float*)d_in[3];
    const float* b2 = (const float*)d_in[4];
    float* out = (float*)d_out;
    char* ws = (char*)d_ws;

    if (ws_size >= WS_NEED) {
        _Float16* Xh   = (_Float16*)(ws + OFF_XH);
        _Float16* Wh   = (_Float16*)(ws + OFF_WH);
        uint32_t* bits = (uint32_t*)(ws + OFF_BITS);

        split_f16<<<2048, 256, 0, stream>>>(x, W1, Xh, Wh);
        fc1_f16<<<dim3(H_DIM / 128, B_ROWS / 256), 512, 0, stream>>>(
            Xh, Wh, x, W1, b1, bits);
        fc2w4<<<B_ROWS / 16, 256, 0, stream>>>(bits, W2, b2, out);
    } else {
        uint32_t* bits = (uint32_t*)ws;
        dim3 g1(H_DIM / BN, B_ROWS / BM);
        snn_fc1<<<g1, 256, 0, stream>>>(x, W1, b1, bits);
        fc2w4<<<B_ROWS / 16, 256, 0, stream>>>(bits, W2, b2, out);
    }
}